// Round 1
// baseline (4986.180 us; speedup 1.0000x reference)
//
#include <hip/hip_runtime.h>
#include <cmath>

#define TT 2048
#define CCH 512
#define NHEAD 8
#define HDIM 64
#define NBATCH 4
#define MROWS (NBATCH * TT)   // 8192

__device__ __forceinline__ float gelu_f(float x) {
    return 0.5f * x * (1.0f + erff(x * 0.70710678118654752440f));
}

// ---------------- LayerNorm over rows of length 512 ----------------
__global__ __launch_bounds__(256)
void ln_rows(const float* __restrict__ in, const float* __restrict__ gam,
             const float* __restrict__ bet, float* __restrict__ out)
{
    const int m = blockIdx.x;
    const int tid = threadIdx.x;
    const float* row = in + (size_t)m * CCH;
    float x0 = row[tid];
    float x1 = row[tid + 256];
    float s  = x0 + x1;
    float sq = x0 * x0 + x1 * x1;
    #pragma unroll
    for (int off = 32; off; off >>= 1) {
        s  += __shfl_xor(s,  off);
        sq += __shfl_xor(sq, off);
    }
    __shared__ float ws[4], wq[4];
    const int wave = tid >> 6, lane = tid & 63;
    if (lane == 0) { ws[wave] = s; wq[wave] = sq; }
    __syncthreads();
    s  = ws[0] + ws[1] + ws[2] + ws[3];
    sq = wq[0] + wq[1] + wq[2] + wq[3];
    const float mean = s * (1.0f / 512.0f);
    const float var  = sq * (1.0f / 512.0f) - mean * mean;
    const float rstd = rsqrtf(var + 1e-5f);
    float* orow = out + (size_t)m * CCH;
    orow[tid]       = (x0 - mean) * rstd * gam[tid]       + bet[tid];
    orow[tid + 256] = (x1 - mean) * rstd * gam[tid + 256] + bet[tid + 256];
}

// ---------------- depthwise conv (k=3, pad 1) + bias + gelu ----------------
__global__ __launch_bounds__(256)
void dwconv_gelu(const float* __restrict__ z, const float* __restrict__ dw,
                 const float* __restrict__ db, float* __restrict__ g)
{
    const int idx = blockIdx.x * 256 + threadIdx.x;   // over 8192*512
    const int c = idx & 511;
    const int m = idx >> 9;
    const int t = m & (TT - 1);
    const float w0 = dw[c * 3 + 0];
    const float w1 = dw[c * 3 + 1];
    const float w2 = dw[c * 3 + 2];
    const float a  = (t > 0)       ? z[idx - CCH] : 0.0f;
    const float b2 = z[idx];
    const float cc = (t < TT - 1)  ? z[idx + CCH] : 0.0f;
    g[idx] = gelu_f(a * w0 + b2 * w1 + cc * w2 + db[c]);
}

// ---------------- generic tiled fp32 GEMM: C = A[M,K] @ Bw[N,K]^T ----------------
enum { EP_BIAS = 0, EP_BIAS_GELU = 1, EP_GELU_RES = 2, EP_BIAS_RES = 3, EP_FINAL = 4 };

template<int EPI, bool CONVA, bool CONVB>
__global__ __launch_bounds__(256)
void gemm_nt(const float* __restrict__ A, const float* __restrict__ Bw,
             const float* __restrict__ bias, const float* __restrict__ res,
             const float* __restrict__ pSa, const float* __restrict__ pSb,
             float* __restrict__ Cc, int M, int N, int K)
{
    __shared__ float As[64][17];
    __shared__ float Bs[64][17];
    const int bm = blockIdx.y * 64;
    const int bn = blockIdx.x * 64;
    const int tid = threadIdx.x;
    const int tx = tid & 15;          // n subtile
    const int ty = tid >> 4;          // m subtile
    float acc[4][4] = {};
    for (int k0 = 0; k0 < K; k0 += 16) {
        #pragma unroll
        for (int e = tid; e < 1024; e += 256) {
            const int r = e >> 4, kk = e & 15;
            const int m = bm + r, k = k0 + kk;
            float v;
            if (CONVA) {
                const int ks = k >> 9, ci = k & 511;
                const int t = m & (TT - 1);
                const int tt = t + ks - 1;
                v = ((unsigned)tt < (unsigned)TT) ? A[(size_t)(m + ks - 1) * CCH + ci] : 0.0f;
            } else {
                v = A[(size_t)m * K + k];
            }
            As[r][kk] = v;
        }
        #pragma unroll
        for (int e = tid; e < 1024; e += 256) {
            const int r = e >> 4, kk = e & 15;
            const int n = bn + r, k = k0 + kk;
            float v;
            if (CONVB) {
                const int ks = k >> 9, ci = k & 511;
                v = Bw[((size_t)n * CCH + ci) * 3 + ks];
            } else {
                v = Bw[(size_t)n * K + k];
            }
            Bs[r][kk] = v;
        }
        __syncthreads();
        #pragma unroll
        for (int kk = 0; kk < 16; ++kk) {
            float a[4], b[4];
            #pragma unroll
            for (int i = 0; i < 4; ++i) a[i] = As[ty * 4 + i][kk];
            #pragma unroll
            for (int j = 0; j < 4; ++j) b[j] = Bs[tx * 4 + j][kk];
            #pragma unroll
            for (int i = 0; i < 4; ++i)
                #pragma unroll
                for (int j = 0; j < 4; ++j)
                    acc[i][j] = fmaf(a[i], b[j], acc[i][j]);
        }
        __syncthreads();
    }
    // epilogue
    float sa = 0.f, sb = 0.f;
    if (EPI == EP_FINAL) { sa = pSa[0]; sb = pSb[0]; }
    #pragma unroll
    for (int i = 0; i < 4; ++i) {
        const int m = bm + ty * 4 + i;
        #pragma unroll
        for (int j = 0; j < 4; ++j) {
            const int n = bn + tx * 4 + j;
            float v = acc[i][j] + bias[n];
            if (EPI == EP_BIAS_GELU) v = gelu_f(v);
            if (EPI == EP_GELU_RES)  v = res[(size_t)m * N + n] + gelu_f(v);
            if (EPI == EP_BIAS_RES)  v = v + res[(size_t)m * N + n];
            if (EPI == EP_FINAL)     v = sa * v + sb * res[(size_t)m * N + n];
            Cc[(size_t)m * N + n] = v;
        }
    }
}

// ---------------- attention: per block = (8 query rows, head, batch) ----------------
__global__ __launch_bounds__(256)
void attn_kernel(const float* __restrict__ qkv, const float* __restrict__ Avec,
                 const float* __restrict__ alpha_p, float* __restrict__ out)
{
    __shared__ float sc[8][TT];       // 64 KB scores
    __shared__ float qs[8][HDIM];     // q rows, prescaled
    __shared__ float part[4][512];    // PV wave partials
    __shared__ float aib[8];
    __shared__ float minv[8];

    const int tid = threadIdx.x;
    const int i0  = blockIdx.x * 8;
    const int h   = blockIdx.y;
    const size_t rowbase = (size_t)blockIdx.z * TT;

    for (int e = tid; e < 512; e += 256) {
        const int i = e >> 6, d = e & 63;
        qs[i][d] = qkv[(rowbase + i0 + i) * 1536 + h * 64 + d] * 0.125f;
    }
    if (tid < 8) aib[tid] = alpha_p[0] * Avec[rowbase + i0 + tid];
    __syncthreads();

    float aire[8];
    #pragma unroll
    for (int i = 0; i < 8; ++i) aire[i] = aib[i];

    // ---- scores: sc[i][j] = (q_i . k_j)/8 + alpha*A_i*A_j ----
    for (int j = tid; j < TT; j += 256) {
        const float4* kp = (const float4*)(qkv + (rowbase + j) * 1536 + 512 + h * 64);
        float4 kv[16];
        #pragma unroll
        for (int q = 0; q < 16; ++q) kv[q] = kp[q];
        float acc[8] = {0.f, 0.f, 0.f, 0.f, 0.f, 0.f, 0.f, 0.f};
        #pragma unroll
        for (int dq = 0; dq < 16; ++dq) {
            const float4 kd = kv[dq];
            #pragma unroll
            for (int i = 0; i < 8; ++i) {
                const float4 qv = *(const float4*)&qs[i][dq * 4];
                acc[i] = fmaf(qv.x, kd.x, acc[i]);
                acc[i] = fmaf(qv.y, kd.y, acc[i]);
                acc[i] = fmaf(qv.z, kd.z, acc[i]);
                acc[i] = fmaf(qv.w, kd.w, acc[i]);
            }
        }
        const float aj = Avec[rowbase + j];
        #pragma unroll
        for (int i = 0; i < 8; ++i) sc[i][j] = acc[i] + aire[i] * aj;
    }
    __syncthreads();

    // ---- softmax per row (4 waves, 2 rows each) ----
    {
        const int wave = tid >> 6, lane = tid & 63;
        for (int i = wave; i < 8; i += 4) {
            float mx = -1e30f;
            for (int jj = lane; jj < TT; jj += 64) mx = fmaxf(mx, sc[i][jj]);
            #pragma unroll
            for (int off = 32; off; off >>= 1) mx = fmaxf(mx, __shfl_xor(mx, off));
            float l = 0.f;
            for (int jj = lane; jj < TT; jj += 64) {
                const float p = __expf(sc[i][jj] - mx);
                sc[i][jj] = p;
                l += p;
            }
            #pragma unroll
            for (int off = 32; off; off >>= 1) l += __shfl_xor(l, off);
            if (lane == 0) minv[i] = 1.0f / l;
        }
    }
    __syncthreads();

    // ---- PV: out[i][d] = sum_j p[i][j] * v[j][d] ----
    {
        const int dq = tid & 15, grp = tid >> 4;
        float accp[8][4] = {};
        for (int j = grp; j < TT; j += 16) {
            const float4 vv = *(const float4*)(qkv + (rowbase + j) * 1536 + 1024 + h * 64 + dq * 4);
            #pragma unroll
            for (int i = 0; i < 8; ++i) {
                const float p = sc[i][j];
                accp[i][0] = fmaf(p, vv.x, accp[i][0]);
                accp[i][1] = fmaf(p, vv.y, accp[i][1]);
                accp[i][2] = fmaf(p, vv.z, accp[i][2]);
                accp[i][3] = fmaf(p, vv.w, accp[i][3]);
            }
        }
        #pragma unroll
        for (int i = 0; i < 8; ++i)
            #pragma unroll
            for (int c = 0; c < 4; ++c) {
                accp[i][c] += __shfl_xor(accp[i][c], 16);
                accp[i][c] += __shfl_xor(accp[i][c], 32);
            }
        const int wave = tid >> 6, lane = tid & 63;
        if (lane < 16) {
            #pragma unroll
            for (int i = 0; i < 8; ++i)
                #pragma unroll
                for (int c = 0; c < 4; ++c)
                    part[wave][i * 64 + lane * 4 + c] = accp[i][c];
        }
    }
    __syncthreads();
    for (int e = tid; e < 512; e += 256) {
        const int i = e >> 6, d = e & 63;
        const float s = part[0][e] + part[1][e] + part[2][e] + part[3][e];
        out[(rowbase + i0 + i) * CCH + h * 64 + d] = s * minv[i];
    }
}

// ---------------- launch ----------------
extern "C" void kernel_launch(void* const* d_in, const int* in_sizes, int n_in,
                              void* d_out, int out_size, void* d_ws, size_t ws_size,
                              hipStream_t stream)
{
    const float* x         = (const float*)d_in[0];
    const float* Avec      = (const float*)d_in[1];
    const float* alpha_b   = (const float*)d_in[2];
    const float* dst_alpha = (const float*)d_in[3];
    const float* dst_beta  = (const float*)d_in[4];
    const float* conv1_w   = (const float*)d_in[5];
    const float* conv1_b   = (const float*)d_in[6];
    const float* ln1_g     = (const float*)d_in[7];
    const float* ln1_b     = (const float*)d_in[8];
    const float* in_proj_w = (const float*)d_in[9];
    const float* in_proj_b = (const float*)d_in[10];
    const float* out_w     = (const float*)d_in[11];
    const float* out_b     = (const float*)d_in[12];
    const float* ln2_g     = (const float*)d_in[13];
    const float* ln2_b     = (const float*)d_in[14];
    const float* mlp_w1    = (const float*)d_in[15];
    const float* mlp_b1    = (const float*)d_in[16];
    const float* mlp_w2    = (const float*)d_in[17];
    const float* mlp_b2    = (const float*)d_in[18];
    const float* dsa_ln_g  = (const float*)d_in[19];
    const float* dsa_ln_b  = (const float*)d_in[20];
    const float* dsa_dw    = (const float*)d_in[21];
    const float* dsa_db    = (const float*)d_in[22];
    const float* dsa_pw    = (const float*)d_in[23];
    const float* dsa_pb    = (const float*)d_in[24];

    float* ws = (float*)d_ws;
    const size_t N1 = (size_t)MROWS * CCH;   // 4,194,304 floats
    float* Z = ws;             // [M,C]
    float* G = ws + N1;        // [M,C]
    float* D = ws + 2 * N1;    // [M,C]
    float* Q = ws + 3 * N1;    // [M, 4C] (qkv uses 3C, t1 uses 4C)

    // --- DSA branch ---
    ln_rows<<<MROWS, 256, 0, stream>>>(x, dsa_ln_g, dsa_ln_b, Z);
    dwconv_gelu<<<(MROWS * CCH) / 256, 256, 0, stream>>>(Z, dsa_dw, dsa_db, G);
    gemm_nt<EP_BIAS, false, false><<<dim3(8, 128), 256, 0, stream>>>(
        G, dsa_pw, dsa_pb, nullptr, nullptr, nullptr, D, MROWS, 512, 512);

    // --- CA branch: conv premix (im2col on the fly), residual, LN1 ---
    gemm_nt<EP_GELU_RES, true, true><<<dim3(8, 128), 256, 0, stream>>>(
        x, conv1_w, conv1_b, x, nullptr, nullptr, G, MROWS, 512, 1536);
    ln_rows<<<MROWS, 256, 0, stream>>>(G, ln1_g, ln1_b, Z);

    // --- qkv projection ---
    gemm_nt<EP_BIAS, false, false><<<dim3(24, 128), 256, 0, stream>>>(
        Z, in_proj_w, in_proj_b, nullptr, nullptr, nullptr, Q, MROWS, 1536, 512);

    // --- attention ---
    attn_kernel<<<dim3(TT / 8, NHEAD, NBATCH), 256, 0, stream>>>(Q, Avec, alpha_b, G);

    // --- out projection + residual, LN2 ---
    gemm_nt<EP_BIAS_RES, false, false><<<dim3(8, 128), 256, 0, stream>>>(
        G, out_w, out_b, x, nullptr, nullptr, Z, MROWS, 512, 512);
    ln_rows<<<MROWS, 256, 0, stream>>>(Z, ln2_g, ln2_b, G);

    // --- MLP ---
    gemm_nt<EP_BIAS_GELU, false, false><<<dim3(32, 128), 256, 0, stream>>>(
        G, mlp_w1, mlp_b1, nullptr, nullptr, nullptr, Q, MROWS, 2048, 512);
    gemm_nt<EP_FINAL, false, false><<<dim3(8, 128), 256, 0, stream>>>(
        Q, mlp_w2, mlp_b2, D, dst_alpha, dst_beta, (float*)d_out, MROWS, 512, 2048);
}

// Round 2
// 696.127 us; speedup vs baseline: 7.1627x; 7.1627x over previous
//
#include <hip/hip_runtime.h>
#include <cmath>

typedef __attribute__((ext_vector_type(8))) short short8;
typedef __attribute__((ext_vector_type(4))) float floatx4;

#define TT 2048
#define CCH 512
#define MROWS 8192
static const size_t N1 = 4194304;   // 8192*512

__device__ __forceinline__ float gelu_f(float x) {
    return 0.5f * x * (1.0f + erff(x * 0.70710678118654752440f));
}
__device__ __forceinline__ unsigned short f2bf(float x) {
    union { float f; unsigned u; } v; v.f = x;
    unsigned r = v.u + 0x7fffu + ((v.u >> 16) & 1u);
    return (unsigned short)(r >> 16);
}
__device__ __forceinline__ float bf2f(unsigned short h) {
    union { unsigned u; float f; } v; v.u = ((unsigned)h) << 16;
    return v.f;
}

// ---------------- weight pack: fp32 -> hi/lo bf16 ----------------
__global__ __launch_bounds__(256)
void pack_w(const float* __restrict__ qkvw, const float* __restrict__ outw,
            const float* __restrict__ w1, const float* __restrict__ w2,
            const float* __restrict__ pw, const float* __restrict__ cv,
            unsigned short* __restrict__ W)
{
    const int idx = blockIdx.x * 256 + threadIdx.x;
    float v;
    if (idx < 786432)            v = qkvw[idx];
    else if (idx < 1048576)      v = outw[idx - 786432];
    else if (idx < 2097152)      v = w1[idx - 1048576];
    else if (idx < 3145728)      v = w2[idx - 2097152];
    else if (idx < 3407872)      v = pw[idx - 3145728];
    else {
        const int l = idx - 3407872;
        const int n = l / 1536, k = l - n * 1536;
        const int ks = k >> 9, ci = k & 511;
        v = cv[n * 1536 + ci * 3 + ks];
    }
    const unsigned short hi = f2bf(v);
    W[idx] = hi;
    W[N1 + idx] = f2bf(v - bf2f(hi));
}

// ---------------- LayerNorm rows of 512 -> hi/lo bf16 ----------------
template<int BHLIN>
__global__ __launch_bounds__(256)
void ln_k(const float* __restrict__ inf, const unsigned short* __restrict__ inh,
          const unsigned short* __restrict__ inl, const float* __restrict__ gam,
          const float* __restrict__ bet, unsigned short* __restrict__ oh,
          unsigned short* __restrict__ ol)
{
    const int m = blockIdx.x, tid = threadIdx.x;
    const size_t i0 = (size_t)m * CCH + tid, i1 = i0 + 256;
    float x0, x1;
    if (BHLIN) { x0 = bf2f(inh[i0]) + bf2f(inl[i0]); x1 = bf2f(inh[i1]) + bf2f(inl[i1]); }
    else       { x0 = inf[i0]; x1 = inf[i1]; }
    float s = x0 + x1, sq = x0 * x0 + x1 * x1;
    #pragma unroll
    for (int off = 32; off; off >>= 1) { s += __shfl_xor(s, off); sq += __shfl_xor(sq, off); }
    __shared__ float ws[4], wq[4];
    const int wave = tid >> 6, lane = tid & 63;
    if (lane == 0) { ws[wave] = s; wq[wave] = sq; }
    __syncthreads();
    s = ws[0] + ws[1] + ws[2] + ws[3];
    sq = wq[0] + wq[1] + wq[2] + wq[3];
    const float mean = s * (1.0f / 512.0f);
    const float var = sq * (1.0f / 512.0f) - mean * mean;
    const float rstd = rsqrtf(var + 1e-5f);
    float y0 = (x0 - mean) * rstd * gam[tid] + bet[tid];
    float y1 = (x1 - mean) * rstd * gam[tid + 256] + bet[tid + 256];
    unsigned short h0 = f2bf(y0), h1 = f2bf(y1);
    oh[i0] = h0; ol[i0] = f2bf(y0 - bf2f(h0));
    oh[i1] = h1; ol[i1] = f2bf(y1 - bf2f(h1));
}

// ---------------- depthwise conv k=3 + bias + gelu, bhl->bhl ----------------
__global__ __launch_bounds__(256)
void dwconv_k(const unsigned short* __restrict__ zh, const unsigned short* __restrict__ zl,
              const float* __restrict__ dw, const float* __restrict__ db,
              unsigned short* __restrict__ gh, unsigned short* __restrict__ gl)
{
    const int idx = blockIdx.x * 256 + threadIdx.x;
    const int c = idx & 511, m = idx >> 9, t = m & (TT - 1);
    const float w0 = dw[c * 3], w1 = dw[c * 3 + 1], w2 = dw[c * 3 + 2];
    const float a  = (t > 0)      ? bf2f(zh[idx - 512]) + bf2f(zl[idx - 512]) : 0.0f;
    const float b  = bf2f(zh[idx]) + bf2f(zl[idx]);
    const float cc = (t < TT - 1) ? bf2f(zh[idx + 512]) + bf2f(zl[idx + 512]) : 0.0f;
    const float v = gelu_f(a * w0 + b * w1 + cc * w2 + db[c]);
    const unsigned short h = f2bf(v);
    gh[idx] = h; gl[idx] = f2bf(v - bf2f(h));
}

// ---------------- bf16x3 MFMA GEMM: C = A[M,K] @ W[N,K]^T ----------------
// EPI: 0=qkv-split  1=bias->bhl  2=gelu+res->bhl  3=bias+res->bhl  4=gelu->bf16  5=final
// AF : 0=A bhl      1=A fp32 im2col(conv premix)  2=A plain bf16
template<int EPI, int AF>
__global__ __launch_bounds__(256)
void gemm_k(const unsigned short* __restrict__ Ah, const unsigned short* __restrict__ Al,
            const float* __restrict__ Af,
            const unsigned short* __restrict__ Bh, const unsigned short* __restrict__ Bl,
            const float* __restrict__ bias, const float* __restrict__ resf,
            const unsigned short* __restrict__ dh, const unsigned short* __restrict__ dl,
            const float* __restrict__ sA, const float* __restrict__ sB,
            float* __restrict__ outf,
            unsigned short* __restrict__ o1, unsigned short* __restrict__ o2,
            unsigned short* __restrict__ o3,
            int M, int Nn, int K)
{
    __shared__ unsigned short AsH[128 * 32];
    __shared__ unsigned short AsL[128 * 32];
    __shared__ unsigned short BsH[128 * 32];
    __shared__ unsigned short BsL[128 * 32];

    const int tid = threadIdx.x;
    const int bm = blockIdx.y * 128, bn = blockIdx.x * 128;
    const int lane = tid & 63, w = tid >> 6;
    const int wr = w >> 1, wc = w & 1;
    const int lr = lane & 15, g = lane >> 4;

    floatx4 acc[4][4];
    #pragma unroll
    for (int mi = 0; mi < 4; ++mi)
        #pragma unroll
        for (int nj = 0; nj < 4; ++nj)
            acc[mi][nj] = (floatx4){0.f, 0.f, 0.f, 0.f};

    for (int k0 = 0; k0 < K; k0 += 32) {
        #pragma unroll
        for (int i = 0; i < 2; ++i) {
            const int chunk = tid + i * 256;
            const int r = chunk >> 2, c = chunk & 3;
            const int kk = k0 + c * 8;
            if (AF == 0 || AF == 2) {
                const size_t ga = (size_t)(bm + r) * K + kk;
                *(short8*)&AsH[r * 32 + c * 8] = *(const short8*)&Ah[ga];
                if (AF == 0) *(short8*)&AsL[r * 32 + c * 8] = *(const short8*)&Al[ga];
            } else {
                const int m = bm + r;
                const int ks = kk >> 9, ci = kk & 511;
                const int t = m & (TT - 1);
                const int tt = t + ks - 1;
                const float* src = Af + (size_t)(m + ks - 1) * 512 + ci;
                short8 hv, lv;
                #pragma unroll
                for (int j = 0; j < 8; ++j) {
                    const float xv = ((unsigned)tt < (unsigned)TT) ? src[j] : 0.0f;
                    const unsigned short h = f2bf(xv);
                    hv[j] = (short)h;
                    lv[j] = (short)f2bf(xv - bf2f(h));
                }
                *(short8*)&AsH[r * 32 + c * 8] = hv;
                *(short8*)&AsL[r * 32 + c * 8] = lv;
            }
            const size_t gb = (size_t)(bn + r) * K + kk;
            *(short8*)&BsH[r * 32 + c * 8] = *(const short8*)&Bh[gb];
            *(short8*)&BsL[r * 32 + c * 8] = *(const short8*)&Bl[gb];
        }
        __syncthreads();

        short8 av[4], alv[4], bv[4], blv[4];
        #pragma unroll
        for (int mi = 0; mi < 4; ++mi) {
            const int row = wr * 64 + mi * 16 + lr;
            av[mi] = *(const short8*)&AsH[row * 32 + g * 8];
            if (AF != 2) alv[mi] = *(const short8*)&AsL[row * 32 + g * 8];
        }
        #pragma unroll
        for (int nj = 0; nj < 4; ++nj) {
            const int row = wc * 64 + nj * 16 + lr;
            bv[nj] = *(const short8*)&BsH[row * 32 + g * 8];
            blv[nj] = *(const short8*)&BsL[row * 32 + g * 8];
        }
        #pragma unroll
        for (int mi = 0; mi < 4; ++mi)
            #pragma unroll
            for (int nj = 0; nj < 4; ++nj) {
                acc[mi][nj] = __builtin_amdgcn_mfma_f32_16x16x32_bf16(av[mi], bv[nj], acc[mi][nj], 0, 0, 0);
                acc[mi][nj] = __builtin_amdgcn_mfma_f32_16x16x32_bf16(av[mi], blv[nj], acc[mi][nj], 0, 0, 0);
                if (AF != 2)
                    acc[mi][nj] = __builtin_amdgcn_mfma_f32_16x16x32_bf16(alv[mi], bv[nj], acc[mi][nj], 0, 0, 0);
            }
        __syncthreads();
    }

    float sa = 0.f, sb = 0.f;
    if (EPI == 5) { sa = sA[0]; sb = sB[0]; }
    #pragma unroll
    for (int mi = 0; mi < 4; ++mi)
        #pragma unroll
        for (int nj = 0; nj < 4; ++nj)
            #pragma unroll
            for (int reg = 0; reg < 4; ++reg) {
                const int m = bm + wr * 64 + mi * 16 + g * 4 + reg;
                const int n = bn + wc * 64 + nj * 16 + lr;
                float v = acc[mi][nj][reg] + bias[n];
                if (EPI == 0) {
                    const int b = m >> 11, t = m & (TT - 1);
                    if (n < 512) {
                        o1[(size_t)m * 512 + n] = f2bf(v * 0.125f);
                    } else if (n < 1024) {
                        o2[(size_t)m * 512 + (n - 512)] = f2bf(v);
                    } else {
                        const int c = n - 1024;
                        o3[(size_t)(b * 8 + (c >> 6)) * 64 * TT + (size_t)(c & 63) * TT + t] = f2bf(v);
                    }
                } else if (EPI == 1) {
                    const unsigned short h = f2bf(v);
                    o1[(size_t)m * 512 + n] = h;
                    o2[(size_t)m * 512 + n] = f2bf(v - bf2f(h));
                } else if (EPI == 2) {
                    v = resf[(size_t)m * 512 + n] + gelu_f(v);
                    const unsigned short h = f2bf(v);
                    o1[(size_t)m * 512 + n] = h;
                    o2[(size_t)m * 512 + n] = f2bf(v - bf2f(h));
                } else if (EPI == 3) {
                    v += resf[(size_t)m * 512 + n];
                    const unsigned short h = f2bf(v);
                    o1[(size_t)m * 512 + n] = h;
                    o2[(size_t)m * 512 + n] = f2bf(v - bf2f(h));
                } else if (EPI == 4) {
                    o1[(size_t)m * Nn + n] = f2bf(gelu_f(v));
                } else {
                    const float d = bf2f(dh[(size_t)m * 512 + n]) + bf2f(dl[(size_t)m * 512 + n]);
                    outf[(size_t)m * 512 + n] = sa * v + sb * d;
                }
            }
}

// ---------------- MFMA flash attention: QBLK=128, KVBLK=64, 4 waves ----------------
__global__ __launch_bounds__(256)
void attn_k(const unsigned short* __restrict__ Qb, const unsigned short* __restrict__ Kb,
            const unsigned short* __restrict__ Vtg, const float* __restrict__ Avec,
            const float* __restrict__ alpha_p,
            unsigned short* __restrict__ Oh, unsigned short* __restrict__ Ol)
{
    __shared__ unsigned short Kt[64 * 64];
    __shared__ unsigned short Vtt[64 * 64];
    __shared__ unsigned short Pl[4 * 32 * 64];

    const int tid = threadIdx.x;
    const int w = tid >> 6, lane = tid & 63;
    const int lr = lane & 15, g = lane >> 4;
    const int i0 = blockIdx.x * 128;
    const int h = blockIdx.y, b = blockIdx.z;
    const float alpha = alpha_p[0];
    const float* Ab = Avec + b * TT;

    // Q fragments (A-layout), q already scaled by 1/8
    short8 qf[2][2];
    #pragma unroll
    for (int fr = 0; fr < 2; ++fr)
        #pragma unroll
        for (int kk = 0; kk < 2; ++kk)
            qf[fr][kk] = *(const short8*)&Qb[(size_t)(b * TT + i0 + w * 32 + fr * 16 + lr) * 512
                                             + h * 64 + kk * 32 + g * 8];
    float aiv[2][4];
    #pragma unroll
    for (int fr = 0; fr < 2; ++fr)
        #pragma unroll
        for (int reg = 0; reg < 4; ++reg)
            aiv[fr][reg] = alpha * Ab[i0 + w * 32 + fr * 16 + g * 4 + reg];

    float mrow[2][4], lrow[2][4];
    floatx4 o[2][4];
    #pragma unroll
    for (int fr = 0; fr < 2; ++fr)
        #pragma unroll
        for (int x = 0; x < 4; ++x) {
            mrow[fr][x] = -1e30f; lrow[fr][x] = 0.f;
            o[fr][x] = (floatx4){0.f, 0.f, 0.f, 0.f};
        }

    for (int kv0 = 0; kv0 < TT; kv0 += 64) {
        // stage K-tile and V^T-tile (XOR-swizzled rows)
        #pragma unroll
        for (int i = 0; i < 2; ++i) {
            const int chunk = tid + i * 256;
            const int j = chunk >> 3, c = chunk & 7;
            short8 kv = *(const short8*)&Kb[(size_t)(b * TT + kv0 + j) * 512 + h * 64 + c * 8];
            *(short8*)&Kt[j * 64 + (((c * 16) ^ ((j & 7) << 4)) >> 1)] = kv;
            short8 vv = *(const short8*)&Vtg[(size_t)((b * 8 + h) * 64 + j) * TT + kv0 + c * 8];
            *(short8*)&Vtt[j * 64 + (((c * 16) ^ ((j & 7) << 4)) >> 1)] = vv;
        }
        __syncthreads();

        // S = Q K^T (+ rank-1 bias)
        floatx4 s[2][4];
        float ajv[4];
        #pragma unroll
        for (int fc = 0; fc < 4; ++fc) {
            const int row = fc * 16 + lr;
            const short8 kf0 = *(const short8*)&Kt[row * 64 + (((g * 16) ^ ((row & 7) << 4)) >> 1)];
            const short8 kf1 = *(const short8*)&Kt[row * 64 + (((64 + g * 16) ^ ((row & 7) << 4)) >> 1)];
            ajv[fc] = Ab[kv0 + fc * 16 + lr];
            #pragma unroll
            for (int fr = 0; fr < 2; ++fr) {
                floatx4 t = (floatx4){0.f, 0.f, 0.f, 0.f};
                t = __builtin_amdgcn_mfma_f32_16x16x32_bf16(qf[fr][0], kf0, t, 0, 0, 0);
                t = __builtin_amdgcn_mfma_f32_16x16x32_bf16(qf[fr][1], kf1, t, 0, 0, 0);
                s[fr][fc] = t;
            }
        }
        #pragma unroll
        for (int fr = 0; fr < 2; ++fr)
            #pragma unroll
            for (int fc = 0; fc < 4; ++fc)
                #pragma unroll
                for (int reg = 0; reg < 4; ++reg)
                    s[fr][fc][reg] += aiv[fr][reg] * ajv[fc];

        // online softmax
        #pragma unroll
        for (int fr = 0; fr < 2; ++fr)
            #pragma unroll
            for (int reg = 0; reg < 4; ++reg) {
                float mx = fmaxf(fmaxf(s[fr][0][reg], s[fr][1][reg]),
                                 fmaxf(s[fr][2][reg], s[fr][3][reg]));
                #pragma unroll
                for (int off = 1; off < 16; off <<= 1) mx = fmaxf(mx, __shfl_xor(mx, off));
                const float mn = fmaxf(mrow[fr][reg], mx);
                const float f = __expf(mrow[fr][reg] - mn);
                mrow[fr][reg] = mn;
                float rs = 0.f;
                #pragma unroll
                for (int fc = 0; fc < 4; ++fc) {
                    const float p = __expf(s[fr][fc][reg] - mn);
                    s[fr][fc][reg] = p;
                    rs += p;
                }
                #pragma unroll
                for (int off = 1; off < 16; off <<= 1) rs += __shfl_xor(rs, off);
                lrow[fr][reg] = lrow[fr][reg] * f + rs;
                #pragma unroll
                for (int fd = 0; fd < 4; ++fd) o[fr][fd][reg] *= f;
            }

        // P -> LDS (bf16, per-wave region), then PV
        #pragma unroll
        for (int fr = 0; fr < 2; ++fr)
            #pragma unroll
            for (int fc = 0; fc < 4; ++fc)
                #pragma unroll
                for (int reg = 0; reg < 4; ++reg) {
                    const int row = fr * 16 + g * 4 + reg;
                    const int col = fc * 16 + lr;
                    Pl[w * 2048 + row * 64 + (((col * 2) ^ ((row & 7) << 4)) >> 1)] = f2bf(s[fr][fc][reg]);
                }

        short8 pa[2][2];
        #pragma unroll
        for (int fr = 0; fr < 2; ++fr)
            #pragma unroll
            for (int kk = 0; kk < 2; ++kk) {
                const int row = fr * 16 + lr;
                pa[fr][kk] = *(const short8*)&Pl[w * 2048 + row * 64
                              + (((kk * 64 + g * 16) ^ ((row & 7) << 4)) >> 1)];
            }
        #pragma unroll
        for (int fd = 0; fd < 4; ++fd)
            #pragma unroll
            for (int kk = 0; kk < 2; ++kk) {
                const int row = fd * 16 + lr;
                const short8 vf = *(const short8*)&Vtt[row * 64
                                   + (((kk * 64 + g * 16) ^ ((row & 7) << 4)) >> 1)];
                #pragma unroll
                for (int fr = 0; fr < 2; ++fr)
                    o[fr][fd] = __builtin_amdgcn_mfma_f32_16x16x32_bf16(pa[fr][kk], vf, o[fr][fd], 0, 0, 0);
            }
        __syncthreads();
    }

    // epilogue: normalize, write hi/lo bf16
    #pragma unroll
    for (int fr = 0; fr < 2; ++fr)
        #pragma unroll
        for (int reg = 0; reg < 4; ++reg) {
            const float inv = 1.0f / lrow[fr][reg];
            const size_t m = (size_t)(b * TT + i0 + w * 32 + fr * 16 + g * 4 + reg);
            #pragma unroll
            for (int fd = 0; fd < 4; ++fd) {
                const float val = o[fr][fd][reg] * inv;
                const int col = h * 64 + fd * 16 + lr;
                const unsigned short hh = f2bf(val);
                Oh[m * 512 + col] = hh;
                Ol[m * 512 + col] = f2bf(val - bf2f(hh));
            }
        }
}

// ---------------- launch ----------------
extern "C" void kernel_launch(void* const* d_in, const int* in_sizes, int n_in,
                              void* d_out, int out_size, void* d_ws, size_t ws_size,
                              hipStream_t stream)
{
    const float* x         = (const float*)d_in[0];
    const float* Avec      = (const float*)d_in[1];
    const float* alpha_b   = (const float*)d_in[2];
    const float* dst_alpha = (const float*)d_in[3];
    const float* dst_beta  = (const float*)d_in[4];
    const float* conv1_w   = (const float*)d_in[5];
    const float* conv1_b   = (const float*)d_in[6];
    const float* ln1_g     = (const float*)d_in[7];
    const float* ln1_b     = (const float*)d_in[8];
    const float* in_proj_w = (const float*)d_in[9];
    const float* in_proj_b = (const float*)d_in[10];
    const float* out_w     = (const float*)d_in[11];
    const float* out_b     = (const float*)d_in[12];
    const float* ln2_g     = (const float*)d_in[13];
    const float* ln2_b     = (const float*)d_in[14];
    const float* mlp_w1    = (const float*)d_in[15];
    const float* mlp_b1    = (const float*)d_in[16];
    const float* mlp_w2    = (const float*)d_in[17];
    const float* mlp_b2    = (const float*)d_in[18];
    const float* dsa_ln_g  = (const float*)d_in[19];
    const float* dsa_ln_b  = (const float*)d_in[20];
    const float* dsa_dw    = (const float*)d_in[21];
    const float* dsa_db    = (const float*)d_in[22];
    const float* dsa_pw    = (const float*)d_in[23];
    const float* dsa_pb    = (const float*)d_in[24];

    float* ws = (float*)d_ws;
    unsigned short* W   = (unsigned short*)ws;                 // weights hi[0,N1) lo[N1,2N1)
    unsigned short* U1h = (unsigned short*)(ws + N1);          unsigned short* U1l = U1h + N1;
    unsigned short* U2h = (unsigned short*)(ws + 2 * N1);      unsigned short* U2l = U2h + N1;
    unsigned short* U3h = (unsigned short*)(ws + 3 * N1);      unsigned short* U3l = U3h + N1;
    unsigned short* Qb  = (unsigned short*)(ws + 4 * N1);
    unsigned short* Kbf = Qb + N1;
    unsigned short* Vtg = (unsigned short*)(ws + 5 * N1);
    unsigned short* Tb  = (unsigned short*)(ws + 4 * N1);      // [8192][2048] bf16, reuses Q/K/Vt

    const unsigned short* Wh = W;
    const unsigned short* Wl = W + N1;
    const int off_qkv = 0, off_out = 786432, off_w1 = 1048576,
              off_w2 = 2097152, off_pw = 3145728, off_cv = 3407872;

    // weight packing
    pack_w<<<16384, 256, 0, stream>>>(in_proj_w, out_w, mlp_w1, mlp_w2, dsa_pw, conv1_w, W);

    // --- DSA branch ---
    ln_k<0><<<MROWS, 256, 0, stream>>>(x, nullptr, nullptr, dsa_ln_g, dsa_ln_b, U1h, U1l);
    dwconv_k<<<16384, 256, 0, stream>>>(U1h, U1l, dsa_dw, dsa_db, U2h, U2l);
    gemm_k<1, 0><<<dim3(4, 64), 256, 0, stream>>>(U2h, U2l, nullptr, Wh + off_pw, Wl + off_pw,
        dsa_pb, nullptr, nullptr, nullptr, nullptr, nullptr, nullptr, U3h, U3l, nullptr,
        MROWS, 512, 512);

    // --- CA branch: conv premix + residual ---
    gemm_k<2, 1><<<dim3(4, 64), 256, 0, stream>>>(nullptr, nullptr, x, Wh + off_cv, Wl + off_cv,
        conv1_b, x, nullptr, nullptr, nullptr, nullptr, nullptr, U1h, U1l, nullptr,
        MROWS, 512, 1536);
    ln_k<1><<<MROWS, 256, 0, stream>>>(nullptr, U1h, U1l, ln1_g, ln1_b, U2h, U2l);

    // --- qkv projection (writes q*0.125, k, and v transposed) ---
    gemm_k<0, 0><<<dim3(12, 64), 256, 0, stream>>>(U2h, U2l, nullptr, Wh + off_qkv, Wl + off_qkv,
        in_proj_b, nullptr, nullptr, nullptr, nullptr, nullptr, nullptr, Qb, Kbf, Vtg,
        MROWS, 1536, 512);

    // --- attention ---
    attn_k<<<dim3(16, 8, 4), 256, 0, stream>>>(Qb, Kbf, Vtg, Avec, alpha_b, U1h, U1l);

    // --- out projection + residual ---
    gemm_k<3, 0><<<dim3(4, 64), 256, 0, stream>>>(U1h, U1l, nullptr, Wh + off_out, Wl + off_out,
        out_b, x, nullptr, nullptr, nullptr, nullptr, nullptr, U2h, U2l, nullptr,
        MROWS, 512, 512);
    ln_k<1><<<MROWS, 256, 0, stream>>>(nullptr, U2h, U2l, ln2_g, ln2_b, U1h, U1l);

    // --- MLP ---
    gemm_k<4, 0><<<dim3(16, 64), 256, 0, stream>>>(U1h, U1l, nullptr, Wh + off_w1, Wl + off_w1,
        mlp_b1, nullptr, nullptr, nullptr, nullptr, nullptr, nullptr, Tb, nullptr, nullptr,
        MROWS, 2048, 512);
    gemm_k<5, 2><<<dim3(4, 64), 256, 0, stream>>>(Tb, nullptr, nullptr, Wh + off_w2, Wl + off_w2,
        mlp_b2, nullptr, U3h, U3l, dst_alpha, dst_beta, (float*)d_out, nullptr, nullptr, nullptr,
        MROWS, 512, 2048);
}

// Round 3
// 391.389 us; speedup vs baseline: 12.7397x; 1.7786x over previous
//
#include <hip/hip_runtime.h>
#include <cmath>

typedef __attribute__((ext_vector_type(8))) short short8;
typedef __attribute__((ext_vector_type(4))) float floatx4;

#define TT 2048
#define CCH 512
#define MROWS 8192
static const size_t N1 = 4194304;   // 8192*512 elements

__device__ __forceinline__ float gelu_f(float x) {
    return 0.5f * x * (1.0f + erff(x * 0.70710678118654752440f));
}
__device__ __forceinline__ unsigned short f2bf(float x) {
    union { float f; unsigned u; } v; v.f = x;
    unsigned r = v.u + 0x7fffu + ((v.u >> 16) & 1u);
    return (unsigned short)(r >> 16);
}
__device__ __forceinline__ float bf2f(unsigned short h) {
    union { unsigned u; float f; } v; v.u = ((unsigned)h) << 16;
    return v.f;
}
__device__ __forceinline__ void gld16(const unsigned short* g, unsigned short* l) {
    __builtin_amdgcn_global_load_lds(
        (const __attribute__((address_space(1))) void*)g,
        (__attribute__((address_space(3))) void*)l, 16, 0, 0);
}

// ---------------- weight pack: fp32 -> bf16 (conv weights re-laid-out) ----------------
__global__ __launch_bounds__(256)
void pack_w(const float* __restrict__ qkvw, const float* __restrict__ outw,
            const float* __restrict__ w1, const float* __restrict__ w2,
            const float* __restrict__ pw, const float* __restrict__ cv,
            unsigned short* __restrict__ W)
{
    const int idx = blockIdx.x * 256 + threadIdx.x;
    float v;
    if (idx < 786432)            v = qkvw[idx];
    else if (idx < 1048576)      v = outw[idx - 786432];
    else if (idx < 2097152)      v = w1[idx - 1048576];
    else if (idx < 3145728)      v = w2[idx - 2097152];
    else if (idx < 3407872)      v = pw[idx - 3145728];
    else {
        const int l = idx - 3407872;
        const int n = l / 1536, k = l - n * 1536;
        const int ks = k >> 9, ci = k & 511;
        v = cv[n * 1536 + ci * 3 + ks];
    }
    W[idx] = f2bf(v);
}

// ---------------- fused: xpad bf16 (zero-padded rows) + DSA LayerNorm ----------------
__global__ __launch_bounds__(256)
void pack_x(const float* __restrict__ x, const float* __restrict__ gam,
            const float* __restrict__ bet, unsigned short* __restrict__ z,
            unsigned short* __restrict__ xpad)
{
    const int m = blockIdx.x, tid = threadIdx.x;
    const int b = m >> 11, t = m & (TT - 1);
    const float2 xv = *(const float2*)&x[(size_t)m * 512 + 2 * tid];
    float s = xv.x + xv.y, sq = xv.x * xv.x + xv.y * xv.y;
    #pragma unroll
    for (int off = 32; off; off >>= 1) { s += __shfl_xor(s, off); sq += __shfl_xor(sq, off); }
    __shared__ float ws[4], wq[4];
    const int wave = tid >> 6, lane = tid & 63;
    if (lane == 0) { ws[wave] = s; wq[wave] = sq; }
    __syncthreads();
    s = ws[0] + ws[1] + ws[2] + ws[3];
    sq = wq[0] + wq[1] + wq[2] + wq[3];
    const float mean = s * (1.0f / 512.0f);
    const float var = sq * (1.0f / 512.0f) - mean * mean;
    const float rstd = rsqrtf(var + 1e-5f);
    const float y0 = (xv.x - mean) * rstd * gam[2 * tid]     + bet[2 * tid];
    const float y1 = (xv.y - mean) * rstd * gam[2 * tid + 1] + bet[2 * tid + 1];
    *(unsigned*)&z[(size_t)m * 512 + 2 * tid] = ((unsigned)f2bf(y1) << 16) | f2bf(y0);
    *(unsigned*)&xpad[((size_t)(b * (TT + 2) + t + 1)) * 512 + 2 * tid] =
        ((unsigned)f2bf(xv.y) << 16) | f2bf(xv.x);
    if (t == 0)
        *(unsigned*)&xpad[((size_t)(b * (TT + 2))) * 512 + 2 * tid] = 0u;
    if (t == TT - 1)
        *(unsigned*)&xpad[((size_t)(b * (TT + 2) + TT + 1)) * 512 + 2 * tid] = 0u;
}

// ---------------- LayerNorm rows of 512, bf16 -> bf16 ----------------
__global__ __launch_bounds__(256)
void ln_bf(const unsigned short* __restrict__ in, const float* __restrict__ gam,
           const float* __restrict__ bet, unsigned short* __restrict__ out)
{
    const int m = blockIdx.x, tid = threadIdx.x;
    const unsigned pv = *(const unsigned*)&in[(size_t)m * 512 + 2 * tid];
    const float x0 = bf2f((unsigned short)pv), x1 = bf2f((unsigned short)(pv >> 16));
    float s = x0 + x1, sq = x0 * x0 + x1 * x1;
    #pragma unroll
    for (int off = 32; off; off >>= 1) { s += __shfl_xor(s, off); sq += __shfl_xor(sq, off); }
    __shared__ float ws[4], wq[4];
    const int wave = tid >> 6, lane = tid & 63;
    if (lane == 0) { ws[wave] = s; wq[wave] = sq; }
    __syncthreads();
    s = ws[0] + ws[1] + ws[2] + ws[3];
    sq = wq[0] + wq[1] + wq[2] + wq[3];
    const float mean = s * (1.0f / 512.0f);
    const float var = sq * (1.0f / 512.0f) - mean * mean;
    const float rstd = rsqrtf(var + 1e-5f);
    const float y0 = (x0 - mean) * rstd * gam[2 * tid]     + bet[2 * tid];
    const float y1 = (x1 - mean) * rstd * gam[2 * tid + 1] + bet[2 * tid + 1];
    *(unsigned*)&out[(size_t)m * 512 + 2 * tid] = ((unsigned)f2bf(y1) << 16) | f2bf(y0);
}

// ---------------- depthwise conv k=3 + bias + gelu ----------------
__global__ __launch_bounds__(256)
void dwconv_k(const unsigned short* __restrict__ z, const float* __restrict__ dw,
              const float* __restrict__ db, unsigned short* __restrict__ g)
{
    const int m = blockIdx.x, tid = threadIdx.x, t = m & (TT - 1);
    const int c = 2 * tid;
    const size_t base = (size_t)m * 512 + c;
    const unsigned vm = *(const unsigned*)&z[base];
    const unsigned va = (t > 0)      ? *(const unsigned*)&z[base - 512] : 0u;
    const unsigned vc = (t < TT - 1) ? *(const unsigned*)&z[base + 512] : 0u;
    float y[2];
    #pragma unroll
    for (int j = 0; j < 2; ++j) {
        const float a  = bf2f((unsigned short)(va >> (16 * j)));
        const float bb = bf2f((unsigned short)(vm >> (16 * j)));
        const float cc = bf2f((unsigned short)(vc >> (16 * j)));
        const int ch = c + j;
        y[j] = gelu_f(a * dw[ch * 3] + bb * dw[ch * 3 + 1] + cc * dw[ch * 3 + 2] + db[ch]);
    }
    *(unsigned*)&g[base] = ((unsigned)f2bf(y[1]) << 16) | f2bf(y[0]);
}

// ---------------- bf16 MFMA GEMM: C = A[M,K] @ W[N,K]^T ----------------
// EPI: 0=qkv-split  1=bias->bf16  2=gelu+res(f32)->bf16  3=bias+res(f32)->bf16
//      4=bias+gelu->bf16  5=final combine -> f32
// AF : 0=A plain bf16 row-major   1=A from xpad (conv premix im2col)
template<int EPI, int AF, int TM>
__global__ __launch_bounds__(256)
void gemm_k(const unsigned short* __restrict__ A, const unsigned short* __restrict__ Bw,
            const float* __restrict__ bias, const float* __restrict__ resf,
            const unsigned short* __restrict__ dsa,
            const float* __restrict__ sA, const float* __restrict__ sB,
            float* __restrict__ outf, unsigned short* __restrict__ o1,
            unsigned short* __restrict__ o2, unsigned short* __restrict__ o3,
            int M, int Nn, int K)
{
    constexpr int WC = (TM == 128) ? 2 : 4;   // waves along N
    constexpr int MI = 4;
    constexpr int NJ = (TM == 128) ? 4 : 2;
    __shared__ unsigned short As[TM * 32];
    __shared__ unsigned short Bs[128 * 32];

    const int tid = threadIdx.x;
    const int bm = blockIdx.y * TM, bn = blockIdx.x * 128;
    const int lane = tid & 63, w = tid >> 6;
    const int wr = w / WC, wc = w % WC;
    const int lr = lane & 15, g = lane >> 4;

    floatx4 acc[MI][NJ];
    #pragma unroll
    for (int mi = 0; mi < MI; ++mi)
        #pragma unroll
        for (int nj = 0; nj < NJ; ++nj)
            acc[mi][nj] = (floatx4){0.f, 0.f, 0.f, 0.f};

    for (int k0 = 0; k0 < K; k0 += 32) {
        // async stage A (TM*32) and B (128*32), 16B/lane, linear LDS
        #pragma unroll
        for (int i = 0; i < TM / 64; ++i) {
            const int c = tid + i * 256;
            const int r = c >> 2, c8 = c & 3;
            const unsigned short* src;
            if (AF == 1) {
                const int m = bm + r;
                const int b = m >> 11, t = m & (TT - 1);
                const int k = k0 + c8 * 8;
                const int ks = k >> 9, ci = k & 511;
                src = A + ((size_t)(b * (TT + 2) + t + ks) * 512 + ci);
            } else {
                src = A + ((size_t)(bm + r) * K + k0 + c8 * 8);
            }
            gld16(src, &As[(size_t)c * 8]);
        }
        #pragma unroll
        for (int i = 0; i < 2; ++i) {
            const int c = tid + i * 256;
            const int r = c >> 2, c8 = c & 3;
            gld16(Bw + ((size_t)(bn + r) * K + k0 + c8 * 8), &Bs[(size_t)c * 8]);
        }
        __syncthreads();

        short8 av[MI], bv[NJ];
        #pragma unroll
        for (int mi = 0; mi < MI; ++mi) {
            const int row = wr * (MI * 16) + mi * 16 + lr;
            av[mi] = *(const short8*)&As[row * 32 + g * 8];
        }
        #pragma unroll
        for (int nj = 0; nj < NJ; ++nj) {
            const int row = wc * (NJ * 16) + nj * 16 + lr;
            bv[nj] = *(const short8*)&Bs[row * 32 + g * 8];
        }
        #pragma unroll
        for (int mi = 0; mi < MI; ++mi)
            #pragma unroll
            for (int nj = 0; nj < NJ; ++nj)
                acc[mi][nj] = __builtin_amdgcn_mfma_f32_16x16x32_bf16(av[mi], bv[nj], acc[mi][nj], 0, 0, 0);
        __syncthreads();
    }

    float sa = 0.f, sb = 0.f;
    if (EPI == 5) { sa = sA[0]; sb = sB[0]; }
    #pragma unroll
    for (int mi = 0; mi < MI; ++mi)
        #pragma unroll
        for (int nj = 0; nj < NJ; ++nj)
            #pragma unroll
            for (int reg = 0; reg < 4; ++reg) {
                const int m = bm + wr * (MI * 16) + mi * 16 + g * 4 + reg;
                const int n = bn + wc * (NJ * 16) + nj * 16 + lr;
                float v = acc[mi][nj][reg] + bias[n];
                if (EPI == 0) {
                    const int b = m >> 11, t = m & (TT - 1);
                    if (n < 512) {
                        o1[(size_t)m * 512 + n] = f2bf(v * 0.125f);
                    } else if (n < 1024) {
                        o2[(size_t)m * 512 + (n - 512)] = f2bf(v);
                    } else {
                        const int c = n - 1024;
                        o3[(size_t)(b * 8 + (c >> 6)) * 64 * TT + (size_t)(c & 63) * TT + t] = f2bf(v);
                    }
                } else if (EPI == 1) {
                    o1[(size_t)m * 512 + n] = f2bf(v);
                } else if (EPI == 2) {
                    o1[(size_t)m * 512 + n] = f2bf(resf[(size_t)m * 512 + n] + gelu_f(v));
                } else if (EPI == 3) {
                    o1[(size_t)m * 512 + n] = f2bf(v + resf[(size_t)m * 512 + n]);
                } else if (EPI == 4) {
                    o1[(size_t)m * Nn + n] = f2bf(gelu_f(v));
                } else {
                    outf[(size_t)m * 512 + n] = sa * v + sb * bf2f(dsa[(size_t)m * 512 + n]);
                }
            }
}

// ---------------- MFMA flash attention: QBLK=128, KVBLK=64, 4 waves ----------------
__global__ __launch_bounds__(256)
void attn_k(const unsigned short* __restrict__ Qb, const unsigned short* __restrict__ Kb,
            const unsigned short* __restrict__ Vtg, const float* __restrict__ Avec,
            const float* __restrict__ alpha_p, unsigned short* __restrict__ Oh)
{
    __shared__ unsigned short Kt[64 * 64];
    __shared__ unsigned short Vtt[64 * 64];
    __shared__ unsigned short Pl[4 * 32 * 64];

    const int tid = threadIdx.x;
    const int w = tid >> 6, lane = tid & 63;
    const int lr = lane & 15, g = lane >> 4;
    const int i0 = blockIdx.x * 128;
    const int h = blockIdx.y, b = blockIdx.z;
    const float alpha = alpha_p[0];
    const float* Ab = Avec + b * TT;

    short8 qf[2][2];
    #pragma unroll
    for (int fr = 0; fr < 2; ++fr)
        #pragma unroll
        for (int kk = 0; kk < 2; ++kk)
            qf[fr][kk] = *(const short8*)&Qb[(size_t)(b * TT + i0 + w * 32 + fr * 16 + lr) * 512
                                             + h * 64 + kk * 32 + g * 8];
    float aiv[2][4];
    #pragma unroll
    for (int fr = 0; fr < 2; ++fr)
        #pragma unroll
        for (int reg = 0; reg < 4; ++reg)
            aiv[fr][reg] = alpha * Ab[i0 + w * 32 + fr * 16 + g * 4 + reg];

    float mrow[2][4], lrow[2][4];
    floatx4 o[2][4];
    #pragma unroll
    for (int fr = 0; fr < 2; ++fr)
        #pragma unroll
        for (int x = 0; x < 4; ++x) {
            mrow[fr][x] = -1e30f; lrow[fr][x] = 0.f;
            o[fr][x] = (floatx4){0.f, 0.f, 0.f, 0.f};
        }

    for (int kv0 = 0; kv0 < TT; kv0 += 64) {
        #pragma unroll
        for (int i = 0; i < 2; ++i) {
            const int chunk = tid + i * 256;
            const int j = chunk >> 3, c = chunk & 7;
            short8 kv = *(const short8*)&Kb[(size_t)(b * TT + kv0 + j) * 512 + h * 64 + c * 8];
            *(short8*)&Kt[j * 64 + (((c * 16) ^ ((j & 7) << 4)) >> 1)] = kv;
            short8 vv = *(const short8*)&Vtg[(size_t)((b * 8 + h) * 64 + j) * TT + kv0 + c * 8];
            *(short8*)&Vtt[j * 64 + (((c * 16) ^ ((j & 7) << 4)) >> 1)] = vv;
        }
        __syncthreads();

        floatx4 s[2][4];
        float ajv[4];
        #pragma unroll
        for (int fc = 0; fc < 4; ++fc) {
            const int row = fc * 16 + lr;
            const short8 kf0 = *(const short8*)&Kt[row * 64 + (((g * 16) ^ ((row & 7) << 4)) >> 1)];
            const short8 kf1 = *(const short8*)&Kt[row * 64 + (((64 + g * 16) ^ ((row & 7) << 4)) >> 1)];
            ajv[fc] = Ab[kv0 + fc * 16 + lr];
            #pragma unroll
            for (int fr = 0; fr < 2; ++fr) {
                floatx4 t = (floatx4){0.f, 0.f, 0.f, 0.f};
                t = __builtin_amdgcn_mfma_f32_16x16x32_bf16(qf[fr][0], kf0, t, 0, 0, 0);
                t = __builtin_amdgcn_mfma_f32_16x16x32_bf16(qf[fr][1], kf1, t, 0, 0, 0);
                s[fr][fc] = t;
            }
        }
        #pragma unroll
        for (int fr = 0; fr < 2; ++fr)
            #pragma unroll
            for (int fc = 0; fc < 4; ++fc)
                #pragma unroll
                for (int reg = 0; reg < 4; ++reg)
                    s[fr][fc][reg] += aiv[fr][reg] * ajv[fc];

        #pragma unroll
        for (int fr = 0; fr < 2; ++fr)
            #pragma unroll
            for (int reg = 0; reg < 4; ++reg) {
                float mx = fmaxf(fmaxf(s[fr][0][reg], s[fr][1][reg]),
                                 fmaxf(s[fr][2][reg], s[fr][3][reg]));
                #pragma unroll
                for (int off = 1; off < 16; off <<= 1) mx = fmaxf(mx, __shfl_xor(mx, off));
                const float mn = fmaxf(mrow[fr][reg], mx);
                const float f = __expf(mrow[fr][reg] - mn);
                mrow[fr][reg] = mn;
                float rs = 0.f;
                #pragma unroll
                for (int fc = 0; fc < 4; ++fc) {
                    const float p = __expf(s[fr][fc][reg] - mn);
                    s[fr][fc][reg] = p;
                    rs += p;
                }
                #pragma unroll
                for (int off = 1; off < 16; off <<= 1) rs += __shfl_xor(rs, off);
                lrow[fr][reg] = lrow[fr][reg] * f + rs;
                #pragma unroll
                for (int fd = 0; fd < 4; ++fd) o[fr][fd][reg] *= f;
            }

        #pragma unroll
        for (int fr = 0; fr < 2; ++fr)
            #pragma unroll
            for (int fc = 0; fc < 4; ++fc)
                #pragma unroll
                for (int reg = 0; reg < 4; ++reg) {
                    const int row = fr * 16 + g * 4 + reg;
                    const int col = fc * 16 + lr;
                    Pl[w * 2048 + row * 64 + (((col * 2) ^ ((row & 7) << 4)) >> 1)] = f2bf(s[fr][fc][reg]);
                }

        short8 pa[2][2];
        #pragma unroll
        for (int fr = 0; fr < 2; ++fr)
            #pragma unroll
            for (int kk = 0; kk < 2; ++kk) {
                const int row = fr * 16 + lr;
                pa[fr][kk] = *(const short8*)&Pl[w * 2048 + row * 64
                              + (((kk * 64 + g * 16) ^ ((row & 7) << 4)) >> 1)];
            }
        #pragma unroll
        for (int fd = 0; fd < 4; ++fd)
            #pragma unroll
            for (int kk = 0; kk < 2; ++kk) {
                const int row = fd * 16 + lr;
                const short8 vf = *(const short8*)&Vtt[row * 64
                                   + (((kk * 64 + g * 16) ^ ((row & 7) << 4)) >> 1)];
                #pragma unroll
                for (int fr = 0; fr < 2; ++fr)
                    o[fr][fd] = __builtin_amdgcn_mfma_f32_16x16x32_bf16(pa[fr][kk], vf, o[fr][fd], 0, 0, 0);
            }
        __syncthreads();
    }

    #pragma unroll
    for (int fr = 0; fr < 2; ++fr)
        #pragma unroll
        for (int reg = 0; reg < 4; ++reg) {
            const float inv = 1.0f / lrow[fr][reg];
            const size_t m = (size_t)(b * TT + i0 + w * 32 + fr * 16 + g * 4 + reg);
            #pragma unroll
            for (int fd = 0; fd < 4; ++fd)
                Oh[m * 512 + h * 64 + fd * 16 + lr] = f2bf(o[fr][fd][reg] * inv);
        }
}

// ---------------- launch ----------------
extern "C" void kernel_launch(void* const* d_in, const int* in_sizes, int n_in,
                              void* d_out, int out_size, void* d_ws, size_t ws_size,
                              hipStream_t stream)
{
    const float* x         = (const float*)d_in[0];
    const float* Avec      = (const float*)d_in[1];
    const float* alpha_b   = (const float*)d_in[2];
    const float* dst_alpha = (const float*)d_in[3];
    const float* dst_beta  = (const float*)d_in[4];
    const float* conv1_w   = (const float*)d_in[5];
    const float* conv1_b   = (const float*)d_in[6];
    const float* ln1_g     = (const float*)d_in[7];
    const float* ln1_b     = (const float*)d_in[8];
    const float* in_proj_w = (const float*)d_in[9];
    const float* in_proj_b = (const float*)d_in[10];
    const float* out_w     = (const float*)d_in[11];
    const float* out_b     = (const float*)d_in[12];
    const float* ln2_g     = (const float*)d_in[13];
    const float* ln2_b     = (const float*)d_in[14];
    const float* mlp_w1    = (const float*)d_in[15];
    const float* mlp_b1    = (const float*)d_in[16];
    const float* mlp_w2    = (const float*)d_in[17];
    const float* mlp_b2    = (const float*)d_in[18];
    const float* dsa_ln_g  = (const float*)d_in[19];
    const float* dsa_ln_b  = (const float*)d_in[20];
    const float* dsa_dw    = (const float*)d_in[21];
    const float* dsa_db    = (const float*)d_in[22];
    const float* dsa_pw    = (const float*)d_in[23];
    const float* dsa_pb    = (const float*)d_in[24];

    unsigned short* W    = (unsigned short*)d_ws;            // N1
    unsigned short* xpad = W + N1;                           // 4*2050*512
    unsigned short* Qb   = xpad + (size_t)4 * (TT + 2) * 512;
    unsigned short* Kbf  = Qb + N1;
    unsigned short* Vt   = Kbf + N1;
    unsigned short* Zb   = Vt + N1;                          // z; 4th quarter of Tb overlay
    unsigned short* Tb   = Qb;                               // [8192][2048] overlays Qb..Zb
    unsigned short* Gb   = Zb + N1;
    unsigned short* Db   = Gb + N1;
    unsigned short* U1   = Db + N1;
    unsigned short* U2   = U1 + N1;
    unsigned short* U3   = U2 + N1;

    const int off_qkv = 0, off_out = 786432, off_w1 = 1048576,
              off_w2 = 2097152, off_pw = 3145728, off_cv = 3407872;

    pack_w<<<16384, 256, 0, stream>>>(in_proj_w, out_w, mlp_w1, mlp_w2, dsa_pw, conv1_w, W);
    pack_x<<<MROWS, 256, 0, stream>>>(x, dsa_ln_g, dsa_ln_b, Zb, xpad);

    // --- DSA branch ---
    dwconv_k<<<MROWS, 256, 0, stream>>>(Zb, dsa_dw, dsa_db, Gb);
    gemm_k<1, 0, 64><<<dim3(4, 128), 256, 0, stream>>>(Gb, W + off_pw, dsa_pb,
        nullptr, nullptr, nullptr, nullptr, nullptr, Db, nullptr, nullptr, MROWS, 512, 512);

    // --- CA branch: conv premix + residual, LN1 ---
    gemm_k<2, 1, 64><<<dim3(4, 128), 256, 0, stream>>>(xpad, W + off_cv, conv1_b,
        x, nullptr, nullptr, nullptr, nullptr, U1, nullptr, nullptr, MROWS, 512, 1536);
    ln_bf<<<MROWS, 256, 0, stream>>>(U1, ln1_g, ln1_b, U2);

    // --- qkv projection (q*0.125, k, v transposed) ---
    gemm_k<0, 0, 128><<<dim3(12, 64), 256, 0, stream>>>(U2, W + off_qkv, in_proj_b,
        nullptr, nullptr, nullptr, nullptr, nullptr, Qb, Kbf, Vt, MROWS, 1536, 512);

    // --- attention ---
    attn_k<<<dim3(16, 8, 4), 256, 0, stream>>>(Qb, Kbf, Vt, Avec, alpha_b, U1);

    // --- out projection + residual, LN2 ---
    gemm_k<3, 0, 64><<<dim3(4, 128), 256, 0, stream>>>(U1, W + off_out, out_b,
        x, nullptr, nullptr, nullptr, nullptr, U3, nullptr, nullptr, MROWS, 512, 512);
    ln_bf<<<MROWS, 256, 0, stream>>>(U3, ln2_g, ln2_b, U2);

    // --- MLP ---
    gemm_k<4, 0, 128><<<dim3(16, 64), 256, 0, stream>>>(U2, W + off_w1, mlp_b1,
        nullptr, nullptr, nullptr, nullptr, nullptr, Tb, nullptr, nullptr, MROWS, 2048, 512);
    gemm_k<5, 0, 64><<<dim3(4, 128), 256, 0, stream>>>(Tb, W + off_w2, mlp_b2,
        nullptr, Db, dst_alpha, dst_beta, (float*)d_out, nullptr, nullptr, nullptr,
        MROWS, 512, 2048);
}

// Round 4
// 372.968 us; speedup vs baseline: 13.3689x; 1.0494x over previous
//
#include <hip/hip_runtime.h>
#include <cmath>

typedef __attribute__((ext_vector_type(8))) short short8;
typedef __attribute__((ext_vector_type(4))) float floatx4;

#define TT 2048
#define CCH 512
#define MROWS 8192
static const size_t N1 = 4194304;   // 8192*512 elements
#define LOG2E 1.44269504088896340736f

__device__ __forceinline__ float gelu_f(float x) {
    return 0.5f * x * (1.0f + erff(x * 0.70710678118654752440f));
}
__device__ __forceinline__ unsigned short f2bf(float x) {
    union { float f; unsigned u; } v; v.f = x;
    unsigned r = v.u + 0x7fffu + ((v.u >> 16) & 1u);
    return (unsigned short)(r >> 16);
}
__device__ __forceinline__ float bf2f(unsigned short h) {
    union { unsigned u; float f; } v; v.u = ((unsigned)h) << 16;
    return v.f;
}
__device__ __forceinline__ void gld16(const unsigned short* g, unsigned short* l) {
    __builtin_amdgcn_global_load_lds(
        (const __attribute__((address_space(1))) void*)g,
        (__attribute__((address_space(3))) void*)l, 16, 0, 0);
}

// ---------------- weight pack: fp32 -> bf16 (conv weights re-laid-out) ----------------
__global__ __launch_bounds__(256)
void pack_w(const float* __restrict__ qkvw, const float* __restrict__ outw,
            const float* __restrict__ w1, const float* __restrict__ w2,
            const float* __restrict__ pw, const float* __restrict__ cv,
            unsigned short* __restrict__ W)
{
    const int idx = blockIdx.x * 256 + threadIdx.x;
    float v;
    if (idx < 786432)            v = qkvw[idx];
    else if (idx < 1048576)      v = outw[idx - 786432];
    else if (idx < 2097152)      v = w1[idx - 1048576];
    else if (idx < 3145728)      v = w2[idx - 2097152];
    else if (idx < 3407872)      v = pw[idx - 3145728];
    else {
        const int l = idx - 3407872;
        const int n = l / 1536, k = l - n * 1536;
        const int ks = k >> 9, ci = k & 511;
        v = cv[n * 1536 + ci * 3 + ks];
    }
    W[idx] = f2bf(v);
}

// ---------------- fused: xpad bf16 (zero-padded rows) + DSA LayerNorm ----------------
__global__ __launch_bounds__(256)
void pack_x(const float* __restrict__ x, const float* __restrict__ gam,
            const float* __restrict__ bet, unsigned short* __restrict__ z,
            unsigned short* __restrict__ xpad)
{
    const int m = blockIdx.x, tid = threadIdx.x;
    const int b = m >> 11, t = m & (TT - 1);
    const float2 xv = *(const float2*)&x[(size_t)m * 512 + 2 * tid];
    float s = xv.x + xv.y, sq = xv.x * xv.x + xv.y * xv.y;
    #pragma unroll
    for (int off = 32; off; off >>= 1) { s += __shfl_xor(s, off); sq += __shfl_xor(sq, off); }
    __shared__ float ws[4], wq[4];
    const int wave = tid >> 6, lane = tid & 63;
    if (lane == 0) { ws[wave] = s; wq[wave] = sq; }
    __syncthreads();
    s = ws[0] + ws[1] + ws[2] + ws[3];
    sq = wq[0] + wq[1] + wq[2] + wq[3];
    const float mean = s * (1.0f / 512.0f);
    const float var = sq * (1.0f / 512.0f) - mean * mean;
    const float rstd = rsqrtf(var + 1e-5f);
    const float y0 = (xv.x - mean) * rstd * gam[2 * tid]     + bet[2 * tid];
    const float y1 = (xv.y - mean) * rstd * gam[2 * tid + 1] + bet[2 * tid + 1];
    *(unsigned*)&z[(size_t)m * 512 + 2 * tid] = ((unsigned)f2bf(y1) << 16) | f2bf(y0);
    *(unsigned*)&xpad[((size_t)(b * (TT + 2) + t + 1)) * 512 + 2 * tid] =
        ((unsigned)f2bf(xv.y) << 16) | f2bf(xv.x);
    if (t == 0)
        *(unsigned*)&xpad[((size_t)(b * (TT + 2))) * 512 + 2 * tid] = 0u;
    if (t == TT - 1)
        *(unsigned*)&xpad[((size_t)(b * (TT + 2) + TT + 1)) * 512 + 2 * tid] = 0u;
}

// ---------------- LayerNorm rows of 512, bf16 -> bf16 ----------------
__global__ __launch_bounds__(256)
void ln_bf(const unsigned short* __restrict__ in, const float* __restrict__ gam,
           const float* __restrict__ bet, unsigned short* __restrict__ out)
{
    const int m = blockIdx.x, tid = threadIdx.x;
    const unsigned pv = *(const unsigned*)&in[(size_t)m * 512 + 2 * tid];
    const float x0 = bf2f((unsigned short)pv), x1 = bf2f((unsigned short)(pv >> 16));
    float s = x0 + x1, sq = x0 * x0 + x1 * x1;
    #pragma unroll
    for (int off = 32; off; off >>= 1) { s += __shfl_xor(s, off); sq += __shfl_xor(sq, off); }
    __shared__ float ws[4], wq[4];
    const int wave = tid >> 6, lane = tid & 63;
    if (lane == 0) { ws[wave] = s; wq[wave] = sq; }
    __syncthreads();
    s = ws[0] + ws[1] + ws[2] + ws[3];
    sq = wq[0] + wq[1] + wq[2] + wq[3];
    const float mean = s * (1.0f / 512.0f);
    const float var = sq * (1.0f / 512.0f) - mean * mean;
    const float rstd = rsqrtf(var + 1e-5f);
    const float y0 = (x0 - mean) * rstd * gam[2 * tid]     + bet[2 * tid];
    const float y1 = (x1 - mean) * rstd * gam[2 * tid + 1] + bet[2 * tid + 1];
    *(unsigned*)&out[(size_t)m * 512 + 2 * tid] = ((unsigned)f2bf(y1) << 16) | f2bf(y0);
}

// ---------------- depthwise conv k=3 + bias + gelu ----------------
__global__ __launch_bounds__(256)
void dwconv_k(const unsigned short* __restrict__ z, const float* __restrict__ dw,
              const float* __restrict__ db, unsigned short* __restrict__ g)
{
    const int m = blockIdx.x, tid = threadIdx.x, t = m & (TT - 1);
    const int c = 2 * tid;
    const size_t base = (size_t)m * 512 + c;
    const unsigned vm = *(const unsigned*)&z[base];
    const unsigned va = (t > 0)      ? *(const unsigned*)&z[base - 512] : 0u;
    const unsigned vc = (t < TT - 1) ? *(const unsigned*)&z[base + 512] : 0u;
    float y[2];
    #pragma unroll
    for (int j = 0; j < 2; ++j) {
        const float a  = bf2f((unsigned short)(va >> (16 * j)));
        const float bb = bf2f((unsigned short)(vm >> (16 * j)));
        const float cc = bf2f((unsigned short)(vc >> (16 * j)));
        const int ch = c + j;
        y[j] = gelu_f(a * dw[ch * 3] + bb * dw[ch * 3 + 1] + cc * dw[ch * 3 + 2] + db[ch]);
    }
    *(unsigned*)&g[base] = ((unsigned)f2bf(y[1]) << 16) | f2bf(y[0]);
}

// ---------------- bf16 MFMA GEMM, 2-phase prefetch: C = A[M,K] @ W[N,K]^T ----------------
// EPI: 0=qkv-split  1=bias->bf16  2=gelu+res(f32)->bf16  3=bias+res(f32)->bf16
//      4=bias+gelu->bf16  5=final combine -> f32
// AF : 0=A plain bf16 row-major   1=A from xpad (conv premix im2col)
template<int EPI, int AF, int TM>
__global__ __launch_bounds__(256)
void gemm_k(const unsigned short* __restrict__ A, const unsigned short* __restrict__ Bw,
            const float* __restrict__ bias, const float* __restrict__ resf,
            const unsigned short* __restrict__ dsa,
            const float* __restrict__ sA, const float* __restrict__ sB,
            float* __restrict__ outf, unsigned short* __restrict__ o1,
            unsigned short* __restrict__ o2, unsigned short* __restrict__ o3,
            int M, int Nn, int K)
{
    constexpr int WC = (TM == 128) ? 2 : 4;   // waves along N
    constexpr int MI = 4;
    constexpr int NJ = (TM == 128) ? 4 : 2;
    __shared__ unsigned short As[2][TM * 32];
    __shared__ unsigned short Bs[2][128 * 32];

    const int tid = threadIdx.x;
    const int bm = blockIdx.y * TM, bn = blockIdx.x * 128;
    const int lane = tid & 63, w = tid >> 6;
    const int wr = w / WC, wc = w % WC;
    const int lr = lane & 15, g = lane >> 4;

    auto stage = [&](int buf, int k0) {
        #pragma unroll
        for (int i = 0; i < TM / 64; ++i) {
            const int c = tid + i * 256;
            const int r = c >> 2, c8 = c & 3;
            const unsigned short* src;
            if (AF == 1) {
                const int m = bm + r;
                const int b = m >> 11, t = m & (TT - 1);
                const int k = k0 + c8 * 8;
                const int ks = k >> 9, ci = k & 511;
                src = A + ((size_t)(b * (TT + 2) + t + ks) * 512 + ci);
            } else {
                src = A + ((size_t)(bm + r) * K + k0 + c8 * 8);
            }
            gld16(src, &As[buf][(size_t)c * 8]);
        }
        #pragma unroll
        for (int i = 0; i < 2; ++i) {
            const int c = tid + i * 256;
            const int r = c >> 2, c8 = c & 3;
            gld16(Bw + ((size_t)(bn + r) * K + k0 + c8 * 8), &Bs[buf][(size_t)c * 8]);
        }
    };

    floatx4 acc[MI][NJ];
    #pragma unroll
    for (int mi = 0; mi < MI; ++mi)
        #pragma unroll
        for (int nj = 0; nj < NJ; ++nj)
            acc[mi][nj] = (floatx4){0.f, 0.f, 0.f, 0.f};

    const int nt = K >> 5;
    stage(0, 0);
    __syncthreads();
    int cur = 0;
    for (int t = 0; t < nt; ++t) {
        if (t + 1 < nt) stage(cur ^ 1, (t + 1) * 32);

        short8 av[MI], bv[NJ];
        #pragma unroll
        for (int mi = 0; mi < MI; ++mi) {
            const int row = wr * (MI * 16) + mi * 16 + lr;
            av[mi] = *(const short8*)&As[cur][row * 32 + g * 8];
        }
        #pragma unroll
        for (int nj = 0; nj < NJ; ++nj) {
            const int row = wc * (NJ * 16) + nj * 16 + lr;
            bv[nj] = *(const short8*)&Bs[cur][row * 32 + g * 8];
        }
        #pragma unroll
        for (int mi = 0; mi < MI; ++mi)
            #pragma unroll
            for (int nj = 0; nj < NJ; ++nj)
                acc[mi][nj] = __builtin_amdgcn_mfma_f32_16x16x32_bf16(av[mi], bv[nj], acc[mi][nj], 0, 0, 0);
        __syncthreads();
        cur ^= 1;
    }

    float sa = 0.f, sb = 0.f;
    if (EPI == 5) { sa = sA[0]; sb = sB[0]; }
    #pragma unroll
    for (int mi = 0; mi < MI; ++mi)
        #pragma unroll
        for (int nj = 0; nj < NJ; ++nj)
            #pragma unroll
            for (int reg = 0; reg < 4; ++reg) {
                const int m = bm + wr * (MI * 16) + mi * 16 + g * 4 + reg;
                const int n = bn + wc * (NJ * 16) + nj * 16 + lr;
                float v = acc[mi][nj][reg] + bias[n];
                if (EPI == 0) {
                    const int b = m >> 11, t = m & (TT - 1);
                    if (n < 512) {
                        o1[(size_t)m * 512 + n] = f2bf(v * (0.125f * LOG2E));
                    } else if (n < 1024) {
                        o2[(size_t)m * 512 + (n - 512)] = f2bf(v);
                    } else {
                        const int c = n - 1024;
                        o3[(size_t)(b * 8 + (c >> 6)) * 64 * TT + (size_t)(c & 63) * TT + t] = f2bf(v);
                    }
                } else if (EPI == 1) {
                    o1[(size_t)m * 512 + n] = f2bf(v);
                } else if (EPI == 2) {
                    o1[(size_t)m * 512 + n] = f2bf(resf[(size_t)m * 512 + n] + gelu_f(v));
                } else if (EPI == 3) {
                    o1[(size_t)m * 512 + n] = f2bf(v + resf[(size_t)m * 512 + n]);
                } else if (EPI == 4) {
                    o1[(size_t)m * Nn + n] = f2bf(gelu_f(v));
                } else {
                    outf[(size_t)m * 512 + n] = sa * v + sb * bf2f(dsa[(size_t)m * 512 + n]);
                }
            }
}

// ---- MFMA flash attention: QBLK=64 (4 waves x 16 rows), KVBLK=64, dbuf + async stage ----
__global__ __launch_bounds__(256, 4)
void attn_k(const unsigned short* __restrict__ Qb, const unsigned short* __restrict__ Kb,
            const unsigned short* __restrict__ Vtg, const float* __restrict__ Avec,
            const float* __restrict__ alpha_p, unsigned short* __restrict__ Oh)
{
    __shared__ unsigned short Kt[2][64 * 64];   // 16 KB
    __shared__ unsigned short Vt[2][64 * 64];   // 16 KB
    __shared__ unsigned short Pl[4][16 * 64];   // 8 KB

    const int tid = threadIdx.x;
    const int w = tid >> 6, lane = tid & 63;
    const int lr = lane & 15, g = lane >> 4;
    const int i0 = blockIdx.x * 64;
    const int h = blockIdx.y, b = blockIdx.z;
    const float alpha = alpha_p[0] * LOG2E;     // scores live in log2 domain
    const float* Ab = Avec + b * TT;

    // staging addresses (chunk = tid + i*256; row j = chunk>>3, col c8 = chunk&7)
    const int j_s[2]  = { (tid + 0) >> 3, (tid + 256) >> 3 };
    const int c8_s[2] = { (tid + 0) & 7,  (tid + 256) & 7 };

    short8 kreg[2], vreg[2];
    auto load_tiles = [&](int kv0) {
        #pragma unroll
        for (int i = 0; i < 2; ++i) {
            kreg[i] = *(const short8*)&Kb[(size_t)(b * TT + kv0 + j_s[i]) * 512 + h * 64 + c8_s[i] * 8];
            vreg[i] = *(const short8*)&Vtg[(size_t)((b * 8 + h) * 64 + j_s[i]) * TT + kv0 + c8_s[i] * 8];
        }
    };
    auto write_tiles = [&](int buf) {
        #pragma unroll
        for (int i = 0; i < 2; ++i) {
            const int j = j_s[i], c = c8_s[i];
            const int off = j * 64 + (((c * 16) ^ ((j & 7) << 4)) >> 1);
            *(short8*)&Kt[buf][off] = kreg[i];
            *(short8*)&Vt[buf][off] = vreg[i];
        }
    };

    // Q fragments (A-layout); q already scaled by 0.125*log2e
    short8 qf[2];
    #pragma unroll
    for (int kk = 0; kk < 2; ++kk)
        qf[kk] = *(const short8*)&Qb[(size_t)(b * TT + i0 + w * 16 + lr) * 512 + h * 64 + kk * 32 + g * 8];
    float aiv[4];
    #pragma unroll
    for (int reg = 0; reg < 4; ++reg)
        aiv[reg] = alpha * Ab[i0 + w * 16 + g * 4 + reg];

    float mrow[4], lrow[4];
    floatx4 o[4];
    #pragma unroll
    for (int xx = 0; xx < 4; ++xx) {
        mrow[xx] = -1e30f; lrow[xx] = 0.f;
        o[xx] = (floatx4){0.f, 0.f, 0.f, 0.f};
    }

    load_tiles(0);
    write_tiles(0);
    __syncthreads();
    int cur = 0;

    for (int t = 0; t < 32; ++t) {
        const int kv0 = t * 64;
        if (t < 31) load_tiles(kv0 + 64);   // next tile loads in flight during compute

        // S = Q K^T (+ rank-1 bias), log2 domain
        floatx4 s[4];
        float ajv[4];
        #pragma unroll
        for (int fc = 0; fc < 4; ++fc) {
            const int row = fc * 16 + lr;
            const short8 kf0 = *(const short8*)&Kt[cur][row * 64 + (((g * 16) ^ ((row & 7) << 4)) >> 1)];
            const short8 kf1 = *(const short8*)&Kt[cur][row * 64 + (((64 + g * 16) ^ ((row & 7) << 4)) >> 1)];
            ajv[fc] = Ab[kv0 + fc * 16 + lr];
            floatx4 tacc = (floatx4){0.f, 0.f, 0.f, 0.f};
            __builtin_amdgcn_s_setprio(1);
            tacc = __builtin_amdgcn_mfma_f32_16x16x32_bf16(qf[0], kf0, tacc, 0, 0, 0);
            tacc = __builtin_amdgcn_mfma_f32_16x16x32_bf16(qf[1], kf1, tacc, 0, 0, 0);
            __builtin_amdgcn_s_setprio(0);
            s[fc] = tacc;
        }
        #pragma unroll
        for (int fc = 0; fc < 4; ++fc)
            #pragma unroll
            for (int reg = 0; reg < 4; ++reg)
                s[fc][reg] += aiv[reg] * ajv[fc];

        // online softmax (reduce over 16 lanes of lr)
        #pragma unroll
        for (int reg = 0; reg < 4; ++reg) {
            float mx = fmaxf(fmaxf(s[0][reg], s[1][reg]), fmaxf(s[2][reg], s[3][reg]));
            #pragma unroll
            for (int off = 1; off < 16; off <<= 1) mx = fmaxf(mx, __shfl_xor(mx, off));
            const float mn = fmaxf(mrow[reg], mx);
            const float f = exp2f(mrow[reg] - mn);
            mrow[reg] = mn;
            float rs = 0.f;
            #pragma unroll
            for (int fc = 0; fc < 4; ++fc) {
                const float p = exp2f(s[fc][reg] - mn);
                s[fc][reg] = p;
                rs += p;
            }
            #pragma unroll
            for (int off = 1; off < 16; off <<= 1) rs += __shfl_xor(rs, off);
            lrow[reg] = lrow[reg] * f + rs;
            #pragma unroll
            for (int fd = 0; fd < 4; ++fd) o[fd][reg] *= f;
        }

        // P -> LDS (bf16, per-wave region)
        #pragma unroll
        for (int fc = 0; fc < 4; ++fc)
            #pragma unroll
            for (int reg = 0; reg < 4; ++reg) {
                const int row = g * 4 + reg;
                const int col = fc * 16 + lr;
                Pl[w][row * 64 + (((col * 2) ^ ((row & 7) << 4)) >> 1)] = f2bf(s[fc][reg]);
            }

        short8 pa[2];
        #pragma unroll
        for (int kk = 0; kk < 2; ++kk)
            pa[kk] = *(const short8*)&Pl[w][lr * 64 + (((kk * 64 + g * 16) ^ ((lr & 7) << 4)) >> 1)];
        #pragma unroll
        for (int fd = 0; fd < 4; ++fd) {
            #pragma unroll
            for (int kk = 0; kk < 2; ++kk) {
                const int row = fd * 16 + lr;
                const short8 vf = *(const short8*)&Vt[cur][row * 64
                                   + (((kk * 64 + g * 16) ^ ((row & 7) << 4)) >> 1)];
                __builtin_amdgcn_s_setprio(1);
                o[fd] = __builtin_amdgcn_mfma_f32_16x16x32_bf16(pa[kk], vf, o[fd], 0, 0, 0);
                __builtin_amdgcn_s_setprio(0);
            }
        }

        if (t < 31) write_tiles(cur ^ 1);   // other buffer: nobody reads it since t-1's barrier
        __syncthreads();                     // staged writes visible; all waves done with cur
        cur ^= 1;
    }

    #pragma unroll
    for (int reg = 0; reg < 4; ++reg) {
        const float inv = 1.0f / lrow[reg];
        const size_t m = (size_t)(b * TT + i0 + w * 16 + g * 4 + reg);
        #pragma unroll
        for (int fd = 0; fd < 4; ++fd)
            Oh[m * 512 + h * 64 + fd * 16 + lr] = f2bf(o[fd][reg] * inv);
    }
}

// ---------------- launch ----------------
extern "C" void kernel_launch(void* const* d_in, const int* in_sizes, int n_in,
                              void* d_out, int out_size, void* d_ws, size_t ws_size,
                              hipStream_t stream)
{
    const float* x         = (const float*)d_in[0];
    const float* Avec      = (const float*)d_in[1];
    const float* alpha_b   = (const float*)d_in[2];
    const float* dst_alpha = (const float*)d_in[3];
    const float* dst_beta  = (const float*)d_in[4];
    const float* conv1_w   = (const float*)d_in[5];
    const float* conv1_b   = (const float*)d_in[6];
    const float* ln1_g     = (const float*)d_in[7];
    const float* ln1_b     = (const float*)d_in[8];
    const float* in_proj_w = (const float*)d_in[9];
    const float* in_proj_b = (const float*)d_in[10];
    const float* out_w     = (const float*)d_in[11];
    const float* out_b     = (const float*)d_in[12];
    const float* ln2_g     = (const float*)d_in[13];
    const float* ln2_b     = (const float*)d_in[14];
    const float* mlp_w1    = (const float*)d_in[15];
    const float* mlp_b1    = (const float*)d_in[16];
    const float* mlp_w2    = (const float*)d_in[17];
    const float* mlp_b2    = (const float*)d_in[18];
    const float* dsa_ln_g  = (const float*)d_in[19];
    const float* dsa_ln_b  = (const float*)d_in[20];
    const float* dsa_dw    = (const float*)d_in[21];
    const float* dsa_db    = (const float*)d_in[22];
    const float* dsa_pw    = (const float*)d_in[23];
    const float* dsa_pb    = (const float*)d_in[24];

    unsigned short* W    = (unsigned short*)d_ws;            // N1
    unsigned short* xpad = W + N1;                           // 4*2050*512
    unsigned short* Qb   = xpad + (size_t)4 * (TT + 2) * 512;
    unsigned short* Kbf  = Qb + N1;
    unsigned short* Vt   = Kbf + N1;
    unsigned short* Zb   = Vt + N1;
    unsigned short* Tb   = Qb;                               // [8192][2048] overlays Qb..Zb
    unsigned short* Gb   = Zb + N1;
    unsigned short* Db   = Gb + N1;
    unsigned short* U1   = Db + N1;
    unsigned short* U2   = U1 + N1;
    unsigned short* U3   = U2 + N1;

    const int off_qkv = 0, off_out = 786432, off_w1 = 1048576,
              off_w2 = 2097152, off_pw = 3145728, off_cv = 3407872;

    pack_w<<<16384, 256, 0, stream>>>(in_proj_w, out_w, mlp_w1, mlp_w2, dsa_pw, conv1_w, W);
    pack_x<<<MROWS, 256, 0, stream>>>(x, dsa_ln_g, dsa_ln_b, Zb, xpad);

    // --- DSA branch ---
    dwconv_k<<<MROWS, 256, 0, stream>>>(Zb, dsa_dw, dsa_db, Gb);
    gemm_k<1, 0, 64><<<dim3(4, 128), 256, 0, stream>>>(Gb, W + off_pw, dsa_pb,
        nullptr, nullptr, nullptr, nullptr, nullptr, Db, nullptr, nullptr, MROWS, 512, 512);

    // --- CA branch: conv premix + residual, LN1 ---
    gemm_k<2, 1, 64><<<dim3(4, 128), 256, 0, stream>>>(xpad, W + off_cv, conv1_b,
        x, nullptr, nullptr, nullptr, nullptr, U1, nullptr, nullptr, MROWS, 512, 1536);
    ln_bf<<<MROWS, 256, 0, stream>>>(U1, ln1_g, ln1_b, U2);

    // --- qkv projection (q*0.125*log2e, k, v transposed) ---
    gemm_k<0, 0, 128><<<dim3(12, 64), 256, 0, stream>>>(U2, W + off_qkv, in_proj_b,
        nullptr, nullptr, nullptr, nullptr, nullptr, Qb, Kbf, Vt, MROWS, 1536, 512);

    // --- attention ---
    attn_k<<<dim3(32, 8, 4), 256, 0, stream>>>(Qb, Kbf, Vt, Avec, alpha_b, U1);

    // --- out projection + residual, LN2 ---
    gemm_k<3, 0, 64><<<dim3(4, 128), 256, 0, stream>>>(U1, W + off_out, out_b,
        x, nullptr, nullptr, nullptr, nullptr, U3, nullptr, nullptr, MROWS, 512, 512);
    ln_bf<<<MROWS, 256, 0, stream>>>(U3, ln2_g, ln2_b, U2);

    // --- MLP ---
    gemm_k<4, 0, 128><<<dim3(16, 64), 256, 0, stream>>>(U2, W + off_w1, mlp_b1,
        nullptr, nullptr, nullptr, nullptr, nullptr, Tb, nullptr, nullptr, MROWS, 2048, 512);
    gemm_k<5, 0, 64><<<dim3(4, 128), 256, 0, stream>>>(Tb, W + off_w2, mlp_b2,
        nullptr, Db, dst_alpha, dst_beta, (float*)d_out, nullptr, nullptr, nullptr,
        MROWS, 512, 2048);
}

// Round 5
// 319.490 us; speedup vs baseline: 15.6067x; 1.1674x over previous
//
#include <hip/hip_runtime.h>
#include <cmath>

typedef __attribute__((ext_vector_type(8))) short short8;
typedef __attribute__((ext_vector_type(4))) float floatx4;

#define TT 2048
#define CCH 512
#define MROWS 8192
static const size_t N1 = 4194304;   // 8192*512 elements
#define LOG2E 1.44269504088896340736f

__device__ __forceinline__ float gelu_f(float x) {
    return 0.5f * x * (1.0f + erff(x * 0.70710678118654752440f));
}
__device__ __forceinline__ unsigned short f2bf(float x) {
    union { float f; unsigned u; } v; v.f = x;
    unsigned r = v.u + 0x7fffu + ((v.u >> 16) & 1u);
    return (unsigned short)(r >> 16);
}
__device__ __forceinline__ float bf2f(unsigned short h) {
    union { unsigned u; float f; } v; v.u = ((unsigned)h) << 16;
    return v.f;
}
__device__ __forceinline__ unsigned cvtpk(float a, float b) {
    unsigned r;
    asm("v_cvt_pk_bf16_f32 %0, %1, %2" : "=v"(r) : "v"(a), "v"(b));
    return r;
}
__device__ __forceinline__ void gld16(const unsigned short* g, unsigned short* l) {
    __builtin_amdgcn_global_load_lds(
        (const __attribute__((address_space(1))) void*)g,
        (__attribute__((address_space(3))) void*)l, 16, 0, 0);
}

// ---------------- weight pack: fp32 -> bf16 (conv weights re-laid-out) ----------------
__global__ __launch_bounds__(256)
void pack_w(const float* __restrict__ qkvw, const float* __restrict__ outw,
            const float* __restrict__ w1, const float* __restrict__ w2,
            const float* __restrict__ pw, const float* __restrict__ cv,
            unsigned short* __restrict__ W)
{
    const int idx = blockIdx.x * 256 + threadIdx.x;
    float v;
    if (idx < 786432)            v = qkvw[idx];
    else if (idx < 1048576)      v = outw[idx - 786432];
    else if (idx < 2097152)      v = w1[idx - 1048576];
    else if (idx < 3145728)      v = w2[idx - 2097152];
    else if (idx < 3407872)      v = pw[idx - 3145728];
    else {
        const int l = idx - 3407872;
        const int n = l / 1536, k = l - n * 1536;
        const int ks = k >> 9, ci = k & 511;
        v = cv[n * 1536 + ci * 3 + ks];
    }
    W[idx] = f2bf(v);
}

// ---------------- fused: xpad bf16 (zero-padded rows) + DSA LayerNorm ----------------
__global__ __launch_bounds__(256)
void pack_x(const float* __restrict__ x, const float* __restrict__ gam,
            const float* __restrict__ bet, unsigned short* __restrict__ z,
            unsigned short* __restrict__ xpad)
{
    const int m = blockIdx.x, tid = threadIdx.x;
    const int b = m >> 11, t = m & (TT - 1);
    const float2 xv = *(const float2*)&x[(size_t)m * 512 + 2 * tid];
    float s = xv.x + xv.y, sq = xv.x * xv.x + xv.y * xv.y;
    #pragma unroll
    for (int off = 32; off; off >>= 1) { s += __shfl_xor(s, off); sq += __shfl_xor(sq, off); }
    __shared__ float ws[4], wq[4];
    const int wave = tid >> 6, lane = tid & 63;
    if (lane == 0) { ws[wave] = s; wq[wave] = sq; }
    __syncthreads();
    s = ws[0] + ws[1] + ws[2] + ws[3];
    sq = wq[0] + wq[1] + wq[2] + wq[3];
    const float mean = s * (1.0f / 512.0f);
    const float var = sq * (1.0f / 512.0f) - mean * mean;
    const float rstd = rsqrtf(var + 1e-5f);
    const float y0 = (xv.x - mean) * rstd * gam[2 * tid]     + bet[2 * tid];
    const float y1 = (xv.y - mean) * rstd * gam[2 * tid + 1] + bet[2 * tid + 1];
    *(unsigned*)&z[(size_t)m * 512 + 2 * tid] = ((unsigned)f2bf(y1) << 16) | f2bf(y0);
    *(unsigned*)&xpad[((size_t)(b * (TT + 2) + t + 1)) * 512 + 2 * tid] =
        ((unsigned)f2bf(xv.y) << 16) | f2bf(xv.x);
    if (t == 0)
        *(unsigned*)&xpad[((size_t)(b * (TT + 2))) * 512 + 2 * tid] = 0u;
    if (t == TT - 1)
        *(unsigned*)&xpad[((size_t)(b * (TT + 2) + TT + 1)) * 512 + 2 * tid] = 0u;
}

// ---------------- LayerNorm rows of 512, bf16 -> bf16 ----------------
__global__ __launch_bounds__(256)
void ln_bf(const unsigned short* __restrict__ in, const float* __restrict__ gam,
           const float* __restrict__ bet, unsigned short* __restrict__ out)
{
    const int m = blockIdx.x, tid = threadIdx.x;
    const unsigned pv = *(const unsigned*)&in[(size_t)m * 512 + 2 * tid];
    const float x0 = bf2f((unsigned short)pv), x1 = bf2f((unsigned short)(pv >> 16));
    float s = x0 + x1, sq = x0 * x0 + x1 * x1;
    #pragma unroll
    for (int off = 32; off; off >>= 1) { s += __shfl_xor(s, off); sq += __shfl_xor(sq, off); }
    __shared__ float ws[4], wq[4];
    const int wave = tid >> 6, lane = tid & 63;
    if (lane == 0) { ws[wave] = s; wq[wave] = sq; }
    __syncthreads();
    s = ws[0] + ws[1] + ws[2] + ws[3];
    sq = wq[0] + wq[1] + wq[2] + wq[3];
    const float mean = s * (1.0f / 512.0f);
    const float var = sq * (1.0f / 512.0f) - mean * mean;
    const float rstd = rsqrtf(var + 1e-5f);
    const float y0 = (x0 - mean) * rstd * gam[2 * tid]     + bet[2 * tid];
    const float y1 = (x1 - mean) * rstd * gam[2 * tid + 1] + bet[2 * tid + 1];
    *(unsigned*)&out[(size_t)m * 512 + 2 * tid] = ((unsigned)f2bf(y1) << 16) | f2bf(y0);
}

// ---------------- depthwise conv k=3 + bias + gelu ----------------
__global__ __launch_bounds__(256)
void dwconv_k(const unsigned short* __restrict__ z, const float* __restrict__ dw,
              const float* __restrict__ db, unsigned short* __restrict__ g)
{
    const int m = blockIdx.x, tid = threadIdx.x, t = m & (TT - 1);
    const int c = 2 * tid;
    const size_t base = (size_t)m * 512 + c;
    const unsigned vm = *(const unsigned*)&z[base];
    const unsigned va = (t > 0)      ? *(const unsigned*)&z[base - 512] : 0u;
    const unsigned vc = (t < TT - 1) ? *(const unsigned*)&z[base + 512] : 0u;
    float y[2];
    #pragma unroll
    for (int j = 0; j < 2; ++j) {
        const float a  = bf2f((unsigned short)(va >> (16 * j)));
        const float bb = bf2f((unsigned short)(vm >> (16 * j)));
        const float cc = bf2f((unsigned short)(vc >> (16 * j)));
        const int ch = c + j;
        y[j] = gelu_f(a * dw[ch * 3] + bb * dw[ch * 3 + 1] + cc * dw[ch * 3 + 2] + db[ch]);
    }
    *(unsigned*)&g[base] = ((unsigned)f2bf(y[1]) << 16) | f2bf(y[0]);
}

// ---------------- bf16 MFMA GEMM, 2-phase prefetch: C = A[M,K] @ W[N,K]^T ----------------
// EPI: 0=qkv-split  1=bias->bf16  2=gelu+res(f32)->bf16  3=bias+res(f32)->bf16
//      4=bias+gelu->bf16  5=final combine -> f32
// AF : 0=A plain bf16 row-major   1=A from xpad (conv premix im2col)
template<int EPI, int AF, int TM>
__global__ __launch_bounds__(256)
void gemm_k(const unsigned short* __restrict__ A, const unsigned short* __restrict__ Bw,
            const float* __restrict__ bias, const float* __restrict__ resf,
            const unsigned short* __restrict__ dsa,
            const float* __restrict__ sA, const float* __restrict__ sB,
            float* __restrict__ outf, unsigned short* __restrict__ o1,
            unsigned short* __restrict__ o2, unsigned short* __restrict__ o3,
            int M, int Nn, int K)
{
    constexpr int WC = (TM == 128) ? 2 : 4;   // waves along N
    constexpr int MI = 4;
    constexpr int NJ = (TM == 128) ? 4 : 2;
    __shared__ unsigned short As[2][TM * 32];
    __shared__ unsigned short Bs[2][128 * 32];

    const int tid = threadIdx.x;
    const int bm = blockIdx.y * TM, bn = blockIdx.x * 128;
    const int lane = tid & 63, w = tid >> 6;
    const int wr = w / WC, wc = w % WC;
    const int lr = lane & 15, g = lane >> 4;

    auto stage = [&](int buf, int k0) {
        #pragma unroll
        for (int i = 0; i < TM / 64; ++i) {
            const int c = tid + i * 256;
            const int r = c >> 2, c8 = c & 3;
            const unsigned short* src;
            if (AF == 1) {
                const int m = bm + r;
                const int b = m >> 11, t = m & (TT - 1);
                const int k = k0 + c8 * 8;
                const int ks = k >> 9, ci = k & 511;
                src = A + ((size_t)(b * (TT + 2) + t + ks) * 512 + ci);
            } else {
                src = A + ((size_t)(bm + r) * K + k0 + c8 * 8);
            }
            gld16(src, &As[buf][(size_t)c * 8]);
        }
        #pragma unroll
        for (int i = 0; i < 2; ++i) {
            const int c = tid + i * 256;
            const int r = c >> 2, c8 = c & 3;
            gld16(Bw + ((size_t)(bn + r) * K + k0 + c8 * 8), &Bs[buf][(size_t)c * 8]);
        }
    };

    floatx4 acc[MI][NJ];
    #pragma unroll
    for (int mi = 0; mi < MI; ++mi)
        #pragma unroll
        for (int nj = 0; nj < NJ; ++nj)
            acc[mi][nj] = (floatx4){0.f, 0.f, 0.f, 0.f};

    const int nt = K >> 5;
    stage(0, 0);
    __syncthreads();
    int cur = 0;
    for (int t = 0; t < nt; ++t) {
        if (t + 1 < nt) stage(cur ^ 1, (t + 1) * 32);

        short8 av[MI], bv[NJ];
        #pragma unroll
        for (int mi = 0; mi < MI; ++mi) {
            const int row = wr * (MI * 16) + mi * 16 + lr;
            av[mi] = *(const short8*)&As[cur][row * 32 + g * 8];
        }
        #pragma unroll
        for (int nj = 0; nj < NJ; ++nj) {
            const int row = wc * (NJ * 16) + nj * 16 + lr;
            bv[nj] = *(const short8*)&Bs[cur][row * 32 + g * 8];
        }
        #pragma unroll
        for (int mi = 0; mi < MI; ++mi)
            #pragma unroll
            for (int nj = 0; nj < NJ; ++nj)
                acc[mi][nj] = __builtin_amdgcn_mfma_f32_16x16x32_bf16(av[mi], bv[nj], acc[mi][nj], 0, 0, 0);
        __syncthreads();
        cur ^= 1;
    }

    float sa = 0.f, sb = 0.f;
    if (EPI == 5) { sa = sA[0]; sb = sB[0]; }
    #pragma unroll
    for (int mi = 0; mi < MI; ++mi)
        #pragma unroll
        for (int nj = 0; nj < NJ; ++nj)
            #pragma unroll
            for (int reg = 0; reg < 4; ++reg) {
                const int m = bm + wr * (MI * 16) + mi * 16 + g * 4 + reg;
                const int n = bn + wc * (NJ * 16) + nj * 16 + lr;
                float v = acc[mi][nj][reg] + bias[n];
                if (EPI == 0) {
                    const int b = m >> 11, t = m & (TT - 1);
                    if (n < 512) {
                        o1[(size_t)m * 512 + n] = f2bf(v * (0.125f * LOG2E));
                    } else if (n < 1024) {
                        o2[(size_t)m * 512 + (n - 512)] = f2bf(v);
                    } else {
                        const int c = n - 1024;
                        o3[(size_t)(b * 8 + (c >> 6)) * 64 * TT + (size_t)(c & 63) * TT + t] = f2bf(v);
                    }
                } else if (EPI == 1) {
                    o1[(size_t)m * 512 + n] = f2bf(v);
                } else if (EPI == 2) {
                    o1[(size_t)m * 512 + n] = f2bf(resf[(size_t)m * 512 + n] + gelu_f(v));
                } else if (EPI == 3) {
                    o1[(size_t)m * 512 + n] = f2bf(v + resf[(size_t)m * 512 + n]);
                } else if (EPI == 4) {
                    o1[(size_t)m * Nn + n] = f2bf(gelu_f(v));
                } else {
                    outf[(size_t)m * 512 + n] = sa * v + sb * bf2f(dsa[(size_t)m * 512 + n]);
                }
            }
}

// ---- MFMA flash attention, swapped S^T = mfma(K,Q): QBLK=64, KVBLK=64, dbuf ----
// Each thread owns ONE query column (q = i0 + w*16 + lr); m,l are per-thread scalars.
__global__ __launch_bounds__(256, 4)
void attn_k(const unsigned short* __restrict__ Qb, const unsigned short* __restrict__ Kb,
            const unsigned short* __restrict__ Vtg, const float* __restrict__ Avec,
            const float* __restrict__ alpha_p, unsigned short* __restrict__ Oh)
{
    __shared__ unsigned short Kt[2][64 * 64];   // 16 KB, XOR-swizzled rows
    __shared__ unsigned short Vt[2][64 * 64];   // 16 KB (V^T: rows=d, cols=key)
    __shared__ unsigned short P2[4][16 * 64];   // 8 KB  (per-wave P^T spill: [q][key])

    const int tid = threadIdx.x;
    const int w = tid >> 6, lane = tid & 63;
    const int lr = lane & 15, g = lane >> 4;
    const int i0 = blockIdx.x * 64;
    const int h = blockIdx.y, b = blockIdx.z;
    const float* Ab = Avec + b * TT;
    const int q_glob = i0 + w * 16 + lr;
    const float aqs = alpha_p[0] * LOG2E * Ab[q_glob];   // per-thread query-side bias scale

    // staging addresses (chunk = tid + i*256; row j = chunk>>3, col c8 = chunk&7)
    const int j_s[2]  = { (tid + 0) >> 3, (tid + 256) >> 3 };
    const int c8_s[2] = { (tid + 0) & 7,  (tid + 256) & 7 };

    short8 kreg[2], vreg[2];
    auto load_tiles = [&](int kv0) {
        #pragma unroll
        for (int i = 0; i < 2; ++i) {
            kreg[i] = *(const short8*)&Kb[(size_t)(b * TT + kv0 + j_s[i]) * 512 + h * 64 + c8_s[i] * 8];
            vreg[i] = *(const short8*)&Vtg[(size_t)((b * 8 + h) * 64 + j_s[i]) * TT + kv0 + c8_s[i] * 8];
        }
    };
    auto write_tiles = [&](int buf) {
        #pragma unroll
        for (int i = 0; i < 2; ++i) {
            const int j = j_s[i], c = c8_s[i];
            const int off = j * 64 + (((c * 16) ^ ((j & 7) << 4)) >> 1);
            *(short8*)&Kt[buf][off] = kreg[i];
            *(short8*)&Vt[buf][off] = vreg[i];
        }
    };

    // Q fragment (B-operand; same lane mapping as A); q pre-scaled by 0.125*log2e
    short8 qf[2];
    #pragma unroll
    for (int kk = 0; kk < 2; ++kk)
        qf[kk] = *(const short8*)&Qb[(size_t)(b * TT + q_glob) * 512 + h * 64 + kk * 32 + g * 8];

    float m_run = -1e30f, l_run = 0.f;
    floatx4 o[4];
    #pragma unroll
    for (int fd = 0; fd < 4; ++fd) o[fd] = (floatx4){0.f, 0.f, 0.f, 0.f};

    load_tiles(0);
    write_tiles(0);
    __syncthreads();
    int cur = 0;

    for (int t = 0; t < 32; ++t) {
        const int kv0 = t * 64;
        if (t < 31) load_tiles(kv0 + 64);   // next-tile loads in flight during compute

        // S^T[key][q] = K·Q^T (log2 domain); thread holds keys fc*16+g*4+reg for query lr
        floatx4 s[4];
        #pragma unroll
        for (int fc = 0; fc < 4; ++fc) {
            const int row = fc * 16 + lr;
            const short8 kf0 = *(const short8*)&Kt[cur][row * 64 + (((g * 16) ^ ((row & 7) << 4)) >> 1)];
            const short8 kf1 = *(const short8*)&Kt[cur][row * 64 + (((64 + g * 16) ^ ((row & 7) << 4)) >> 1)];
            floatx4 tacc = (floatx4){0.f, 0.f, 0.f, 0.f};
            __builtin_amdgcn_s_setprio(1);
            tacc = __builtin_amdgcn_mfma_f32_16x16x32_bf16(kf0, qf[0], tacc, 0, 0, 0);
            tacc = __builtin_amdgcn_mfma_f32_16x16x32_bf16(kf1, qf[1], tacc, 0, 0, 0);
            __builtin_amdgcn_s_setprio(0);
            s[fc] = tacc;
        }
        // rank-1 bias: += (alpha*log2e*A_q) * A_key
        #pragma unroll
        for (int fc = 0; fc < 4; ++fc) {
            const floatx4 ak = *(const floatx4*)&Ab[kv0 + fc * 16 + g * 4];
            #pragma unroll
            for (int r = 0; r < 4; ++r) s[fc][r] += aqs * ak[r];
        }

        // online softmax: in-reg tree over 16 keys + 2 shuffles across g-groups
        float mx;
        {
            float a0 = fmaxf(fmaxf(s[0][0], s[0][1]), fmaxf(s[0][2], s[0][3]));
            float a1 = fmaxf(fmaxf(s[1][0], s[1][1]), fmaxf(s[1][2], s[1][3]));
            float a2 = fmaxf(fmaxf(s[2][0], s[2][1]), fmaxf(s[2][2], s[2][3]));
            float a3 = fmaxf(fmaxf(s[3][0], s[3][1]), fmaxf(s[3][2], s[3][3]));
            mx = fmaxf(fmaxf(a0, a1), fmaxf(a2, a3));
            mx = fmaxf(mx, __shfl_xor(mx, 16));
            mx = fmaxf(mx, __shfl_xor(mx, 32));
        }
        if (__ballot(mx > m_run + 8.0f)) {   // defer-max: skip rescale while growth <= 2^8
            const float mn = fmaxf(m_run, mx);
            const float f = exp2f(m_run - mn);
            m_run = mn;
            l_run *= f;
            #pragma unroll
            for (int fd = 0; fd < 4; ++fd) o[fd] *= f;
        }
        #pragma unroll
        for (int fc = 0; fc < 4; ++fc)
            #pragma unroll
            for (int r = 0; r < 4; ++r)
                s[fc][r] = exp2f(s[fc][r] - m_run);
        {
            float a0 = (s[0][0] + s[0][1]) + (s[0][2] + s[0][3]);
            float a1 = (s[1][0] + s[1][1]) + (s[1][2] + s[1][3]);
            float a2 = (s[2][0] + s[2][1]) + (s[2][2] + s[2][3]);
            float a3 = (s[3][0] + s[3][1]) + (s[3][2] + s[3][3]);
            float rs = (a0 + a1) + (a2 + a3);
            rs += __shfl_xor(rs, 16);
            rs += __shfl_xor(rs, 32);
            l_run += rs;
        }

        // spill P as bf16 to per-wave LDS [q=lr][key], XOR-swizzled, b64 writes
        #pragma unroll
        for (int fc = 0; fc < 4; ++fc) {
            uint2 pk;
            pk.x = cvtpk(s[fc][0], s[fc][1]);
            pk.y = cvtpk(s[fc][2], s[fc][3]);
            const int boff = (lr * 128 + fc * 32 + g * 8) ^ ((lr & 7) << 4);
            *(uint2*)((char*)&P2[w][0] + boff) = pk;
        }
        // PV B-operand: P[q=lr][k = kk*32 + g*8 + 0..7], b128 reads
        short8 pf[2];
        #pragma unroll
        for (int kk = 0; kk < 2; ++kk) {
            const int boff = (lr * 128 + kk * 64 + g * 16) ^ ((lr & 7) << 4);
            pf[kk] = *(const short8*)((const char*)&P2[w][0] + boff);
        }
        // O^T[d][q] += V^T · P^T : A = V^T rows d, B = P rows q
        #pragma unroll
        for (int fd = 0; fd < 4; ++fd) {
            const int row = fd * 16 + lr;
            const short8 vf0 = *(const short8*)&Vt[cur][row * 64 + (((g * 16) ^ ((row & 7) << 4)) >> 1)];
            const short8 vf1 = *(const short8*)&Vt[cur][row * 64 + (((64 + g * 16) ^ ((row & 7) << 4)) >> 1)];
            __builtin_amdgcn_s_setprio(1);
            o[fd] = __builtin_amdgcn_mfma_f32_16x16x32_bf16(vf0, pf[0], o[fd], 0, 0, 0);
            o[fd] = __builtin_amdgcn_mfma_f32_16x16x32_bf16(vf1, pf[1], o[fd], 0, 0, 0);
            __builtin_amdgcn_s_setprio(0);
        }

        if (t < 31) write_tiles(cur ^ 1);   // other buffer: nobody reads it since last barrier
        __syncthreads();
        cur ^= 1;
    }

    // epilogue: o[fd][reg] = O[q][d = fd*16 + g*4 + reg]; packed dwordx2 stores
    const float inv = 1.0f / l_run;
    const size_t orow = (size_t)(b * TT + q_glob) * 512 + h * 64;
    #pragma unroll
    for (int fd = 0; fd < 4; ++fd) {
        uint2 pk;
        pk.x = cvtpk(o[fd][0] * inv, o[fd][1] * inv);
        pk.y = cvtpk(o[fd][2] * inv, o[fd][3] * inv);
        *(uint2*)&Oh[orow + fd * 16 + g * 4] = pk;
    }
}

// ---------------- launch ----------------
extern "C" void kernel_launch(void* const* d_in, const int* in_sizes, int n_in,
                              void* d_out, int out_size, void* d_ws, size_t ws_size,
                              hipStream_t stream)
{
    const float* x         = (const float*)d_in[0];
    const float* Avec      = (const float*)d_in[1];
    const float* alpha_b   = (const float*)d_in[2];
    const float* dst_alpha = (const float*)d_in[3];
    const float* dst_beta  = (const float*)d_in[4];
    const float* conv1_w   = (const float*)d_in[5];
    const float* conv1_b   = (const float*)d_in[6];
    const float* ln1_g     = (const float*)d_in[7];
    const float* ln1_b     = (const float*)d_in[8];
    const float* in_proj_w = (const float*)d_in[9];
    const float* in_proj_b = (const float*)d_in[10];
    const float* out_w     = (const float*)d_in[11];
    const float* out_b     = (const float*)d_in[12];
    const float* ln2_g     = (const float*)d_in[13];
    const float* ln2_b     = (const float*)d_in[14];
    const float* mlp_w1    = (const float*)d_in[15];
    const float* mlp_b1    = (const float*)d_in[16];
    const float* mlp_w2    = (const float*)d_in[17];
    const float* mlp_b2    = (const float*)d_in[18];
    const float* dsa_ln_g  = (const float*)d_in[19];
    const float* dsa_ln_b  = (const float*)d_in[20];
    const float* dsa_dw    = (const float*)d_in[21];
    const float* dsa_db    = (const float*)d_in[22];
    const float* dsa_pw    = (const float*)d_in[23];
    const float* dsa_pb    = (const float*)d_in[24];

    unsigned short* W    = (unsigned short*)d_ws;            // N1
    unsigned short* xpad = W + N1;                           // 4*2050*512
    unsigned short* Qb   = xpad + (size_t)4 * (TT + 2) * 512;
    unsigned short* Kbf  = Qb + N1;
    unsigned short* Vt   = Kbf + N1;
    unsigned short* Zb   = Vt + N1;
    unsigned short* Tb   = Qb;                               // [8192][2048] overlays Qb..Zb
    unsigned short* Gb   = Zb + N1;
    unsigned short* Db   = Gb + N1;
    unsigned short* U1   = Db + N1;
    unsigned short* U2   = U1 + N1;
    unsigned short* U3   = U2 + N1;

    const int off_qkv = 0, off_out = 786432, off_w1 = 1048576,
              off_w2 = 2097152, off_pw = 3145728, off_cv = 3407872;

    pack_w<<<16384, 256, 0, stream>>>(in_proj_w, out_w, mlp_w1, mlp_w2, dsa_pw, conv1_w, W);
    pack_x<<<MROWS, 256, 0, stream>>>(x, dsa_ln_g, dsa_ln_b, Zb, xpad);

    // --- DSA branch ---
    dwconv_k<<<MROWS, 256, 0, stream>>>(Zb, dsa_dw, dsa_db, Gb);
    gemm_k<1, 0, 64><<<dim3(4, 128), 256, 0, stream>>>(Gb, W + off_pw, dsa_pb,
        nullptr, nullptr, nullptr, nullptr, nullptr, Db, nullptr, nullptr, MROWS, 512, 512);

    // --- CA branch: conv premix + residual, LN1 ---
    gemm_k<2, 1, 64><<<dim3(4, 128), 256, 0, stream>>>(xpad, W + off_cv, conv1_b,
        x, nullptr, nullptr, nullptr, nullptr, U1, nullptr, nullptr, MROWS, 512, 1536);
    ln_bf<<<MROWS, 256, 0, stream>>>(U1, ln1_g, ln1_b, U2);

    // --- qkv projection (q*0.125*log2e, k, v transposed) ---
    gemm_k<0, 0, 128><<<dim3(12, 64), 256, 0, stream>>>(U2, W + off_qkv, in_proj_b,
        nullptr, nullptr, nullptr, nullptr, nullptr, Qb, Kbf, Vt, MROWS, 1536, 512);

    // --- attention ---
    attn_k<<<dim3(32, 8, 4), 256, 0, stream>>>(Qb, Kbf, Vt, Avec, alpha_b, U1);

    // --- out projection + residual, LN2 ---
    gemm_k<3, 0, 64><<<dim3(4, 128), 256, 0, stream>>>(U1, W + off_out, out_b,
        x, nullptr, nullptr, nullptr, nullptr, U3, nullptr, nullptr, MROWS, 512, 512);
    ln_bf<<<MROWS, 256, 0, stream>>>(U3, ln2_g, ln2_b, U2);

    // --- MLP ---
    gemm_k<4, 0, 128><<<dim3(16, 64), 256, 0, stream>>>(U2, W + off_w1, mlp_b1,
        nullptr, nullptr, nullptr, nullptr, nullptr, Tb, nullptr, nullptr, MROWS, 2048, 512);
    gemm_k<5, 0, 64><<<dim3(4, 128), 256, 0, stream>>>(Tb, W + off_w2, mlp_b2,
        nullptr, Db, dst_alpha, dst_beta, (float*)d_out, nullptr, nullptr, nullptr,
        MROWS, 512, 2048);
}

// Round 6
// 316.431 us; speedup vs baseline: 15.7575x; 1.0097x over previous
//
#include <hip/hip_runtime.h>
#include <cmath>

typedef __attribute__((ext_vector_type(8))) short short8;
typedef __attribute__((ext_vector_type(4))) float floatx4;

#define TT 2048
#define CCH 512
#define MROWS 8192
static const size_t N1 = 4194304;   // 8192*512 elements
#define LOG2E 1.44269504088896340736f

__device__ __forceinline__ float gelu_f(float x) {
    return 0.5f * x * (1.0f + erff(x * 0.70710678118654752440f));
}
__device__ __forceinline__ unsigned short f2bf(float x) {
    union { float f; unsigned u; } v; v.f = x;
    unsigned r = v.u + 0x7fffu + ((v.u >> 16) & 1u);
    return (unsigned short)(r >> 16);
}
__device__ __forceinline__ float bf2f(unsigned short h) {
    union { unsigned u; float f; } v; v.u = ((unsigned)h) << 16;
    return v.f;
}
__device__ __forceinline__ unsigned cvtpk(float a, float b) {
    unsigned r;
    asm("v_cvt_pk_bf16_f32 %0, %1, %2" : "=v"(r) : "v"(a), "v"(b));
    return r;
}
__device__ __forceinline__ void gld16(const unsigned short* g, unsigned short* l) {
    __builtin_amdgcn_global_load_lds(
        (const __attribute__((address_space(1))) void*)g,
        (__attribute__((address_space(3))) void*)l, 16, 0, 0);
}

// ---------------- weight pack: fp32 -> bf16 (conv weights re-laid-out) ----------------
__global__ __launch_bounds__(256)
void pack_w(const float* __restrict__ qkvw, const float* __restrict__ outw,
            const float* __restrict__ w1, const float* __restrict__ w2,
            const float* __restrict__ pw, const float* __restrict__ cv,
            unsigned short* __restrict__ W)
{
    const int idx = blockIdx.x * 256 + threadIdx.x;
    float v;
    if (idx < 786432)            v = qkvw[idx];
    else if (idx < 1048576)      v = outw[idx - 786432];
    else if (idx < 2097152)      v = w1[idx - 1048576];
    else if (idx < 3145728)      v = w2[idx - 2097152];
    else if (idx < 3407872)      v = pw[idx - 3145728];
    else {
        const int l = idx - 3407872;
        const int n = l / 1536, k = l - n * 1536;
        const int ks = k >> 9, ci = k & 511;
        v = cv[n * 1536 + ci * 3 + ks];
    }
    W[idx] = f2bf(v);
}

// ---------------- fused: xpad bf16 (zero-padded rows) + DSA LayerNorm ----------------
__global__ __launch_bounds__(256)
void pack_x(const float* __restrict__ x, const float* __restrict__ gam,
            const float* __restrict__ bet, unsigned short* __restrict__ z,
            unsigned short* __restrict__ xpad)
{
    const int m = blockIdx.x, tid = threadIdx.x;
    const int b = m >> 11, t = m & (TT - 1);
    const float2 xv = *(const float2*)&x[(size_t)m * 512 + 2 * tid];
    float s = xv.x + xv.y, sq = xv.x * xv.x + xv.y * xv.y;
    #pragma unroll
    for (int off = 32; off; off >>= 1) { s += __shfl_xor(s, off); sq += __shfl_xor(sq, off); }
    __shared__ float ws[4], wq[4];
    const int wave = tid >> 6, lane = tid & 63;
    if (lane == 0) { ws[wave] = s; wq[wave] = sq; }
    __syncthreads();
    s = ws[0] + ws[1] + ws[2] + ws[3];
    sq = wq[0] + wq[1] + wq[2] + wq[3];
    const float mean = s * (1.0f / 512.0f);
    const float var = sq * (1.0f / 512.0f) - mean * mean;
    const float rstd = rsqrtf(var + 1e-5f);
    const float y0 = (xv.x - mean) * rstd * gam[2 * tid]     + bet[2 * tid];
    const float y1 = (xv.y - mean) * rstd * gam[2 * tid + 1] + bet[2 * tid + 1];
    *(unsigned*)&z[(size_t)m * 512 + 2 * tid] = ((unsigned)f2bf(y1) << 16) | f2bf(y0);
    *(unsigned*)&xpad[((size_t)(b * (TT + 2) + t + 1)) * 512 + 2 * tid] =
        ((unsigned)f2bf(xv.y) << 16) | f2bf(xv.x);
    if (t == 0)
        *(unsigned*)&xpad[((size_t)(b * (TT + 2))) * 512 + 2 * tid] = 0u;
    if (t == TT - 1)
        *(unsigned*)&xpad[((size_t)(b * (TT + 2) + TT + 1)) * 512 + 2 * tid] = 0u;
}

// ---------------- LayerNorm rows of 512, bf16 -> bf16 ----------------
__global__ __launch_bounds__(256)
void ln_bf(const unsigned short* __restrict__ in, const float* __restrict__ gam,
           const float* __restrict__ bet, unsigned short* __restrict__ out)
{
    const int m = blockIdx.x, tid = threadIdx.x;
    const unsigned pv = *(const unsigned*)&in[(size_t)m * 512 + 2 * tid];
    const float x0 = bf2f((unsigned short)pv), x1 = bf2f((unsigned short)(pv >> 16));
    float s = x0 + x1, sq = x0 * x0 + x1 * x1;
    #pragma unroll
    for (int off = 32; off; off >>= 1) { s += __shfl_xor(s, off); sq += __shfl_xor(sq, off); }
    __shared__ float ws[4], wq[4];
    const int wave = tid >> 6, lane = tid & 63;
    if (lane == 0) { ws[wave] = s; wq[wave] = sq; }
    __syncthreads();
    s = ws[0] + ws[1] + ws[2] + ws[3];
    sq = wq[0] + wq[1] + wq[2] + wq[3];
    const float mean = s * (1.0f / 512.0f);
    const float var = sq * (1.0f / 512.0f) - mean * mean;
    const float rstd = rsqrtf(var + 1e-5f);
    const float y0 = (x0 - mean) * rstd * gam[2 * tid]     + bet[2 * tid];
    const float y1 = (x1 - mean) * rstd * gam[2 * tid + 1] + bet[2 * tid + 1];
    *(unsigned*)&out[(size_t)m * 512 + 2 * tid] = ((unsigned)f2bf(y1) << 16) | f2bf(y0);
}

// ---------------- depthwise conv k=3 + bias + gelu ----------------
__global__ __launch_bounds__(256)
void dwconv_k(const unsigned short* __restrict__ z, const float* __restrict__ dw,
              const float* __restrict__ db, unsigned short* __restrict__ g)
{
    const int m = blockIdx.x, tid = threadIdx.x, t = m & (TT - 1);
    const int c = 2 * tid;
    const size_t base = (size_t)m * 512 + c;
    const unsigned vm = *(const unsigned*)&z[base];
    const unsigned va = (t > 0)      ? *(const unsigned*)&z[base - 512] : 0u;
    const unsigned vc = (t < TT - 1) ? *(const unsigned*)&z[base + 512] : 0u;
    float y[2];
    #pragma unroll
    for (int j = 0; j < 2; ++j) {
        const float a  = bf2f((unsigned short)(va >> (16 * j)));
        const float bb = bf2f((unsigned short)(vm >> (16 * j)));
        const float cc = bf2f((unsigned short)(vc >> (16 * j)));
        const int ch = c + j;
        y[j] = gelu_f(a * dw[ch * 3] + bb * dw[ch * 3 + 1] + cc * dw[ch * 3 + 2] + db[ch]);
    }
    *(unsigned*)&g[base] = ((unsigned)f2bf(y[1]) << 16) | f2bf(y[0]);
}

// ------- bf16 MFMA GEMM, 3-buffer counted-vmcnt pipeline: C = A[M,K] @ W[N,K]^T -------
// EPI: 0=qkv-split  1=bias->bf16  2=gelu+res(f32)->bf16  3=bias+res(f32)->bf16
//      4=bias+gelu->bf16  5=final combine -> f32
// AF : 0=A plain bf16 row-major   1=A from xpad (conv premix im2col)
template<int EPI, int AF, int TM>
__global__ __launch_bounds__(256)
void gemm_k(const unsigned short* __restrict__ A, const unsigned short* __restrict__ Bw,
            const float* __restrict__ bias, const float* __restrict__ resf,
            const unsigned short* __restrict__ dsa,
            const float* __restrict__ sA, const float* __restrict__ sB,
            float* __restrict__ outf, unsigned short* __restrict__ o1,
            unsigned short* __restrict__ o2, unsigned short* __restrict__ o3,
            int M, int Nn, int K)
{
    constexpr int WC = (TM == 128) ? 2 : 4;   // waves along N
    constexpr int MI = 4;
    constexpr int NJ = (TM == 128) ? 4 : 2;
    __shared__ unsigned short As[3][TM * 32];
    __shared__ unsigned short Bs[3][128 * 32];

    const int tid = threadIdx.x;
    const int bm = blockIdx.y * TM, bn = blockIdx.x * 128;
    const int lane = tid & 63, w = tid >> 6;
    const int wr = w / WC, wc = w % WC;
    const int lr = lane & 15, g = lane >> 4;

    auto stage = [&](int buf, int k0) {
        #pragma unroll
        for (int i = 0; i < TM / 64; ++i) {
            const int c = tid + i * 256;
            const int r = c >> 2, c8 = c & 3;
            const unsigned short* src;
            if (AF == 1) {
                const int m = bm + r;
                const int b = m >> 11, t = m & (TT - 1);
                const int k = k0 + c8 * 8;
                const int ks = k >> 9, ci = k & 511;
                src = A + ((size_t)(b * (TT + 2) + t + ks) * 512 + ci);
            } else {
                src = A + ((size_t)(bm + r) * K + k0 + c8 * 8);
            }
            gld16(src, &As[buf][(size_t)c * 8]);
        }
        #pragma unroll
        for (int i = 0; i < 2; ++i) {
            const int c = tid + i * 256;
            const int r = c >> 2, c8 = c & 3;
            gld16(Bw + ((size_t)(bn + r) * K + k0 + c8 * 8), &Bs[buf][(size_t)c * 8]);
        }
    };

    floatx4 acc[MI][NJ];
    #pragma unroll
    for (int mi = 0; mi < MI; ++mi)
        #pragma unroll
        for (int nj = 0; nj < NJ; ++nj)
            acc[mi][nj] = (floatx4){0.f, 0.f, 0.f, 0.f};

    const int nt = K >> 5;
    stage(0, 0);
    stage(1, 32);
    for (int t = 0; t < nt; ++t) {
        // wait for stage(t) only (stage(t+1) stays in flight), then barrier
        if (t < nt - 1) {
            if constexpr (TM == 64) asm volatile("s_waitcnt vmcnt(3)" ::: "memory");
            else                    asm volatile("s_waitcnt vmcnt(4)" ::: "memory");
        } else {
            asm volatile("s_waitcnt vmcnt(0)" ::: "memory");
        }
        __builtin_amdgcn_s_barrier();
        __builtin_amdgcn_sched_barrier(0);
        if (t + 2 < nt) stage((t + 2) % 3, (t + 2) * 32);

        const int cur = t % 3;
        short8 av[MI], bv[NJ];
        #pragma unroll
        for (int mi = 0; mi < MI; ++mi) {
            const int row = wr * (MI * 16) + mi * 16 + lr;
            av[mi] = *(const short8*)&As[cur][row * 32 + g * 8];
        }
        #pragma unroll
        for (int nj = 0; nj < NJ; ++nj) {
            const int row = wc * (NJ * 16) + nj * 16 + lr;
            bv[nj] = *(const short8*)&Bs[cur][row * 32 + g * 8];
        }
        __builtin_amdgcn_s_setprio(1);
        #pragma unroll
        for (int mi = 0; mi < MI; ++mi)
            #pragma unroll
            for (int nj = 0; nj < NJ; ++nj)
                acc[mi][nj] = __builtin_amdgcn_mfma_f32_16x16x32_bf16(av[mi], bv[nj], acc[mi][nj], 0, 0, 0);
        __builtin_amdgcn_s_setprio(0);
    }

    float sa = 0.f, sb = 0.f;
    if (EPI == 5) { sa = sA[0]; sb = sB[0]; }
    #pragma unroll
    for (int mi = 0; mi < MI; ++mi)
        #pragma unroll
        for (int nj = 0; nj < NJ; ++nj)
            #pragma unroll
            for (int reg = 0; reg < 4; ++reg) {
                const int m = bm + wr * (MI * 16) + mi * 16 + g * 4 + reg;
                const int n = bn + wc * (NJ * 16) + nj * 16 + lr;
                float v = acc[mi][nj][reg] + bias[n];
                if (EPI == 0) {
                    const int b = m >> 11, t = m & (TT - 1);
                    if (n < 512) {
                        o1[(size_t)m * 512 + n] = f2bf(v * (0.125f * LOG2E));
                    } else if (n < 1024) {
                        o2[(size_t)m * 512 + (n - 512)] = f2bf(v);
                    } else {
                        const int c = n - 1024;
                        o3[(size_t)(b * 8 + (c >> 6)) * 64 * TT + (size_t)(c & 63) * TT + t] = f2bf(v);
                    }
                } else if (EPI == 1) {
                    o1[(size_t)m * 512 + n] = f2bf(v);
                } else if (EPI == 2) {
                    o1[(size_t)m * 512 + n] = f2bf(resf[(size_t)m * 512 + n] + gelu_f(v));
                } else if (EPI == 3) {
                    o1[(size_t)m * 512 + n] = f2bf(v + resf[(size_t)m * 512 + n]);
                } else if (EPI == 4) {
                    o1[(size_t)m * Nn + n] = f2bf(gelu_f(v));
                } else {
                    outf[(size_t)m * 512 + n] = sa * v + sb * bf2f(dsa[(size_t)m * 512 + n]);
                }
            }
}

// ---- MFMA flash attention, swapped S^T = mfma(K,Q): 8 waves, QBLK=128, KVBLK=64 ----
// Max-free softmax (scores are O(few) for this op); each thread owns ONE query.
__global__ __launch_bounds__(512, 2)
void attn_k(const unsigned short* __restrict__ Qb, const unsigned short* __restrict__ Kb,
            const unsigned short* __restrict__ Vtg, const float* __restrict__ Avec,
            const float* __restrict__ alpha_p, unsigned short* __restrict__ Oh)
{
    __shared__ unsigned short Kt[2][64 * 64];   // 16 KB, XOR-swizzled rows
    __shared__ unsigned short Vt[2][64 * 64];   // 16 KB (V^T: rows=d, cols=key)
    __shared__ unsigned short P2[8][16 * 64];   // 16 KB (per-wave P^T spill: [q][key])

    const int tid = threadIdx.x;
    const int w = tid >> 6, lane = tid & 63;
    const int lr = lane & 15, g = lane >> 4;
    const int i0 = blockIdx.x * 128;
    const int h = blockIdx.y, b = blockIdx.z;
    const float* Ab = Avec + b * TT;
    const int q_glob = i0 + w * 16 + lr;
    const float aqs = alpha_p[0] * LOG2E * Ab[q_glob];   // query-side bias scale

    // staging: 512 threads cover a 64x64 bf16 tile with one short8 each
    const int j_s = tid >> 3, c8_s = tid & 7;

    short8 kreg, vreg;
    auto load_tiles = [&](int kv0) {
        kreg = *(const short8*)&Kb[(size_t)(b * TT + kv0 + j_s) * 512 + h * 64 + c8_s * 8];
        vreg = *(const short8*)&Vtg[(size_t)((b * 8 + h) * 64 + j_s) * TT + kv0 + c8_s * 8];
    };
    auto write_tiles = [&](int buf) {
        const int off = j_s * 64 + (((c8_s * 16) ^ ((j_s & 7) << 4)) >> 1);
        *(short8*)&Kt[buf][off] = kreg;
        *(short8*)&Vt[buf][off] = vreg;
    };

    // Q fragment (B-operand); q pre-scaled by 0.125*log2e
    short8 qf[2];
    #pragma unroll
    for (int kk = 0; kk < 2; ++kk)
        qf[kk] = *(const short8*)&Qb[(size_t)(b * TT + q_glob) * 512 + h * 64 + kk * 32 + g * 8];

    float l_run = 0.f;
    floatx4 o[4];
    #pragma unroll
    for (int fd = 0; fd < 4; ++fd) o[fd] = (floatx4){0.f, 0.f, 0.f, 0.f};

    load_tiles(0);
    write_tiles(0);
    __syncthreads();
    int cur = 0;

    for (int t = 0; t < 32; ++t) {
        const int kv0 = t * 64;
        if (t < 31) load_tiles(kv0 + 64);   // next-tile loads in flight during compute

        // S^T[key][q] = K·Q^T (log2 domain); thread holds keys fc*16+g*4+reg for query lr
        floatx4 s[4];
        #pragma unroll
        for (int fc = 0; fc < 4; ++fc) {
            const int row = fc * 16 + lr;
            const short8 kf0 = *(const short8*)&Kt[cur][row * 64 + (((g * 16) ^ ((row & 7) << 4)) >> 1)];
            const short8 kf1 = *(const short8*)&Kt[cur][row * 64 + (((64 + g * 16) ^ ((row & 7) << 4)) >> 1)];
            floatx4 tacc = (floatx4){0.f, 0.f, 0.f, 0.f};
            __builtin_amdgcn_s_setprio(1);
            tacc = __builtin_amdgcn_mfma_f32_16x16x32_bf16(kf0, qf[0], tacc, 0, 0, 0);
            tacc = __builtin_amdgcn_mfma_f32_16x16x32_bf16(kf1, qf[1], tacc, 0, 0, 0);
            __builtin_amdgcn_s_setprio(0);
            s[fc] = tacc;
        }
        // bias + exp2 (no max tracking) + row-sum
        float rs = 0.f;
        #pragma unroll
        for (int fc = 0; fc < 4; ++fc) {
            const floatx4 ak = *(const floatx4*)&Ab[kv0 + fc * 16 + g * 4];
            #pragma unroll
            for (int r = 0; r < 4; ++r) {
                const float p = exp2f(s[fc][r] + aqs * ak[r]);
                s[fc][r] = p;
                rs += p;
            }
        }
        rs += __shfl_xor(rs, 16);
        rs += __shfl_xor(rs, 32);
        l_run += rs;

        // spill P as bf16 to per-wave LDS [q=lr][key], XOR-swizzled, b64 writes
        #pragma unroll
        for (int fc = 0; fc < 4; ++fc) {
            uint2 pk;
            pk.x = cvtpk(s[fc][0], s[fc][1]);
            pk.y = cvtpk(s[fc][2], s[fc][3]);
            const int boff = (lr * 128 + fc * 32 + g * 8) ^ ((lr & 7) << 4);
            *(uint2*)((char*)&P2[w][0] + boff) = pk;
        }
        short8 pf[2];
        #pragma unroll
        for (int kk = 0; kk < 2; ++kk) {
            const int boff = (lr * 128 + kk * 64 + g * 16) ^ ((lr & 7) << 4);
            pf[kk] = *(const short8*)((const char*)&P2[w][0] + boff);
        }
        // O^T[d][q] += V^T · P^T
        #pragma unroll
        for (int fd = 0; fd < 4; ++fd) {
            const int row = fd * 16 + lr;
            const short8 vf0 = *(const short8*)&Vt[cur][row * 64 + (((g * 16) ^ ((row & 7) << 4)) >> 1)];
            const short8 vf1 = *(const short8*)&Vt[cur][row * 64 + (((64 + g * 16) ^ ((row & 7) << 4)) >> 1)];
            __builtin_amdgcn_s_setprio(1);
            o[fd] = __builtin_amdgcn_mfma_f32_16x16x32_bf16(vf0, pf[0], o[fd], 0, 0, 0);
            o[fd] = __builtin_amdgcn_mfma_f32_16x16x32_bf16(vf1, pf[1], o[fd], 0, 0, 0);
            __builtin_amdgcn_s_setprio(0);
        }

        if (t < 31) write_tiles(cur ^ 1);   // other buffer: all reads of it ended last barrier
        __syncthreads();
        cur ^= 1;
    }

    // epilogue: packed dwordx2 stores
    const float inv = 1.0f / l_run;
    const size_t orow = (size_t)(b * TT + q_glob) * 512 + h * 64;
    #pragma unroll
    for (int fd = 0; fd < 4; ++fd) {
        uint2 pk;
        pk.x = cvtpk(o[fd][0] * inv, o[fd][1] * inv);
        pk.y = cvtpk(o[fd][2] * inv, o[fd][3] * inv);
        *(uint2*)&Oh[orow + fd * 16 + g * 4] = pk;
    }
}

// ---------------- launch ----------------
extern "C" void kernel_launch(void* const* d_in, const int* in_sizes, int n_in,
                              void* d_out, int out_size, void* d_ws, size_t ws_size,
                              hipStream_t stream)
{
    const float* x         = (const float*)d_in[0];
    const float* Avec      = (const float*)d_in[1];
    const float* alpha_b   = (const float*)d_in[2];
    const float* dst_alpha = (const float*)d_in[3];
    const float* dst_beta  = (const float*)d_in[4];
    const float* conv1_w   = (const float*)d_in[5];
    const float* conv1_b   = (const float*)d_in[6];
    const float* ln1_g     = (const float*)d_in[7];
    const float* ln1_b     = (const float*)d_in[8];
    const float* in_proj_w = (const float*)d_in[9];
    const float* in_proj_b = (const float*)d_in[10];
    const float* out_w     = (const float*)d_in[11];
    const float* out_b     = (const float*)d_in[12];
    const float* ln2_g     = (const float*)d_in[13];
    const float* ln2_b     = (const float*)d_in[14];
    const float* mlp_w1    = (const float*)d_in[15];
    const float* mlp_b1    = (const float*)d_in[16];
    const float* mlp_w2    = (const float*)d_in[17];
    const float* mlp_b2    = (const float*)d_in[18];
    const float* dsa_ln_g  = (const float*)d_in[19];
    const float* dsa_ln_b  = (const float*)d_in[20];
    const float* dsa_dw    = (const float*)d_in[21];
    const float* dsa_db    = (const float*)d_in[22];
    const float* dsa_pw    = (const float*)d_in[23];
    const float* dsa_pb    = (const float*)d_in[24];

    unsigned short* W    = (unsigned short*)d_ws;            // N1
    unsigned short* xpad = W + N1;                           // 4*2050*512
    unsigned short* Qb   = xpad + (size_t)4 * (TT + 2) * 512;
    unsigned short* Kbf  = Qb + N1;
    unsigned short* Vt   = Kbf + N1;
    unsigned short* Zb   = Vt + N1;
    unsigned short* Tb   = Qb;                               // [8192][2048] overlays Qb..Zb
    unsigned short* Gb   = Zb + N1;
    unsigned short* Db   = Gb + N1;
    unsigned short* U1   = Db + N1;
    unsigned short* U2   = U1 + N1;
    unsigned short* U3   = U2 + N1;

    const int off_qkv = 0, off_out = 786432, off_w1 = 1048576,
              off_w2 = 2097152, off_pw = 3145728, off_cv = 3407872;

    pack_w<<<16384, 256, 0, stream>>>(in_proj_w, out_w, mlp_w1, mlp_w2, dsa_pw, conv1_w, W);
    pack_x<<<MROWS, 256, 0, stream>>>(x, dsa_ln_g, dsa_ln_b, Zb, xpad);

    // --- DSA branch ---
    dwconv_k<<<MROWS, 256, 0, stream>>>(Zb, dsa_dw, dsa_db, Gb);
    gemm_k<1, 0, 64><<<dim3(4, 128), 256, 0, stream>>>(Gb, W + off_pw, dsa_pb,
        nullptr, nullptr, nullptr, nullptr, nullptr, Db, nullptr, nullptr, MROWS, 512, 512);

    // --- CA branch: conv premix + residual, LN1 ---
    gemm_k<2, 1, 64><<<dim3(4, 128), 256, 0, stream>>>(xpad, W + off_cv, conv1_b,
        x, nullptr, nullptr, nullptr, nullptr, U1, nullptr, nullptr, MROWS, 512, 1536);
    ln_bf<<<MROWS, 256, 0, stream>>>(U1, ln1_g, ln1_b, U2);

    // --- qkv projection (q*0.125*log2e, k, v transposed) ---
    gemm_k<0, 0, 128><<<dim3(12, 64), 256, 0, stream>>>(U2, W + off_qkv, in_proj_b,
        nullptr, nullptr, nullptr, nullptr, nullptr, Qb, Kbf, Vt, MROWS, 1536, 512);

    // --- attention ---
    attn_k<<<dim3(16, 8, 4), 512, 0, stream>>>(Qb, Kbf, Vt, Avec, alpha_b, U1);

    // --- out projection + residual, LN2 ---
    gemm_k<3, 0, 64><<<dim3(4, 128), 256, 0, stream>>>(U1, W + off_out, out_b,
        x, nullptr, nullptr, nullptr, nullptr, U3, nullptr, nullptr, MROWS, 512, 512);
    ln_bf<<<MROWS, 256, 0, stream>>>(U3, ln2_g, ln2_b, U2);

    // --- MLP ---
    gemm_k<4, 0, 128><<<dim3(16, 64), 256, 0, stream>>>(U2, W + off_w1, mlp_b1,
        nullptr, nullptr, nullptr, nullptr, nullptr, Tb, nullptr, nullptr, MROWS, 2048, 512);
    gemm_k<5, 0, 64><<<dim3(4, 128), 256, 0, stream>>>(Tb, W + off_w2, mlp_b2,
        nullptr, Db, dst_alpha, dst_beta, (float*)d_out, nullptr, nullptr, nullptr,
        MROWS, 512, 2048);
}